// Round 1
// baseline (1228.566 us; speedup 1.0000x reference)
//
#include <hip/hip_runtime.h>

#define S_LEN 2048
#define HID_D 2048
#define NH 16
#define NHK 4
#define HD 128
#define ATT_SCALE 0.08838834764831845f   // 128^-0.5
#define NEG_INF (-3.0e38f)

// ---------------------------------------------------------------------------
// Generic fp32 GEMM tile: C[M,N] = A[M,K] @ B[K,N], all row-major.
// 128x128 block tile, K-step 16, 256 threads, 8x8 micro-tile.
// As stored transposed [k][row] (pad 132) for vectorized conflict-free reads.
// ---------------------------------------------------------------------------
__device__ __forceinline__ void gemm_tile(const float* __restrict__ A,
                                          const float* __restrict__ B,
                                          float* __restrict__ C,
                                          int N, int K, int bm, int bn) {
  __shared__ float As[16][132];   // [k][row]
  __shared__ float Bs[16][128];   // [k][col]
  const int tid = threadIdx.x;
  const int tx = tid & 15, ty = tid >> 4;

  float acc[8][8];
#pragma unroll
  for (int i = 0; i < 8; ++i)
#pragma unroll
    for (int j = 0; j < 8; ++j) acc[i][j] = 0.f;

  for (int k0 = 0; k0 < K; k0 += 16) {
    // A tile: 128 rows x 16 k, float4 along k, store transposed.
#pragma unroll
    for (int l = 0; l < 2; ++l) {
      int f = tid + 256 * l;            // 0..511
      int row = f >> 2;                 // 0..127
      int kk4 = (f & 3) << 2;           // 0,4,8,12
      const float4 a = *reinterpret_cast<const float4*>(
          &A[(size_t)(bm + row) * K + k0 + kk4]);
      As[kk4 + 0][row] = a.x;
      As[kk4 + 1][row] = a.y;
      As[kk4 + 2][row] = a.z;
      As[kk4 + 3][row] = a.w;
    }
    // B tile: 16 rows x 128 cols.
#pragma unroll
    for (int l = 0; l < 2; ++l) {
      int f = tid + 256 * l;            // 0..511
      int row = f >> 5;                 // 0..15
      int c4 = (f & 31) << 2;
      *reinterpret_cast<float4*>(&Bs[row][c4]) =
          *reinterpret_cast<const float4*>(&B[(size_t)(k0 + row) * N + bn + c4]);
    }
    __syncthreads();

#pragma unroll
    for (int kk = 0; kk < 16; ++kk) {
      float av[8], bv[8];
      *reinterpret_cast<float4*>(&av[0]) =
          *reinterpret_cast<const float4*>(&As[kk][ty * 4]);
      *reinterpret_cast<float4*>(&av[4]) =
          *reinterpret_cast<const float4*>(&As[kk][64 + ty * 4]);
      *reinterpret_cast<float4*>(&bv[0]) =
          *reinterpret_cast<const float4*>(&Bs[kk][tx * 4]);
      *reinterpret_cast<float4*>(&bv[4]) =
          *reinterpret_cast<const float4*>(&Bs[kk][64 + tx * 4]);
#pragma unroll
      for (int i = 0; i < 8; ++i)
#pragma unroll
        for (int j = 0; j < 8; ++j)
          acc[i][j] = fmaf(av[i], bv[j], acc[i][j]);
    }
    __syncthreads();
  }

#pragma unroll
  for (int i = 0; i < 8; ++i) {
    int r = bm + ((i < 4) ? (ty * 4 + i) : (64 + ty * 4 + (i - 4)));
    float4 c0 = make_float4(acc[i][0], acc[i][1], acc[i][2], acc[i][3]);
    float4 c1 = make_float4(acc[i][4], acc[i][5], acc[i][6], acc[i][7]);
    *reinterpret_cast<float4*>(&C[(size_t)r * N + bn + tx * 4]) = c0;
    *reinterpret_cast<float4*>(&C[(size_t)r * N + bn + 64 + tx * 4]) = c1;
  }
}

// Fused QKV projection: hs[2048,2048] @ {Wq,Wk,Wv}.
__global__ __launch_bounds__(256) void qkv_proj_kernel(
    const float* __restrict__ hs, const float* __restrict__ Wq,
    const float* __restrict__ Wk, const float* __restrict__ Wv,
    float* __restrict__ Qb, float* __restrict__ Kb, float* __restrict__ Vb) {
  const int bx = blockIdx.x;
  const int bm = blockIdx.y * 128;
  const float* Bp;
  float* Cp;
  int N, bn;
  if (bx < 16)      { Bp = Wq; Cp = Qb; N = 2048; bn = bx * 128; }
  else if (bx < 20) { Bp = Wk; Cp = Kb; N = 512;  bn = (bx - 16) * 128; }
  else              { Bp = Wv; Cp = Vb; N = 512;  bn = (bx - 20) * 128; }
  gemm_tile(hs, Bp, Cp, N, HID_D, bm, bn);
}

__global__ __launch_bounds__(256) void out_proj_kernel(
    const float* __restrict__ Ob, const float* __restrict__ Wo,
    float* __restrict__ out) {
  gemm_tile(Ob, Wo, out, HID_D, NH * HD, blockIdx.y * 128, blockIdx.x * 128);
}

// ---------------------------------------------------------------------------
// In-place RoPE on first 64 dims of each head. Pair (i, i+32), i in [0,32):
//   out[i]    = q[i]*cos[i]    - q[i+32]*sin[i]
//   out[i+32] = q[i+32]*cos[i+32] + q[i]*sin[i+32]
// ---------------------------------------------------------------------------
__global__ __launch_bounds__(256) void rope_kernel(
    float* __restrict__ Qb, float* __restrict__ Kb,
    const float* __restrict__ cs, const float* __restrict__ sn) {
  const int idx = blockIdx.x * 256 + threadIdx.x;
  const int QP = S_LEN * NH * 32;
  const int KP = S_LEN * NHK * 32;
  if (idx < QP) {
    int i = idx & 31;
    int h = (idx >> 5) & (NH - 1);
    int s = idx >> 9;
    float* p = Qb + (size_t)s * (NH * HD) + h * HD + i;
    float c0 = cs[s * 64 + i], c1 = cs[s * 64 + 32 + i];
    float s0 = sn[s * 64 + i], s1 = sn[s * 64 + 32 + i];
    float lo = p[0], hi = p[32];
    p[0]  = lo * c0 - hi * s0;
    p[32] = hi * c1 + lo * s1;
  } else if (idx < QP + KP) {
    int j = idx - QP;
    int i = j & 31;
    int hk = (j >> 5) & (NHK - 1);
    int s = j >> 7;
    float* p = Kb + (size_t)s * (NHK * HD) + hk * HD + i;
    float c0 = cs[s * 64 + i], c1 = cs[s * 64 + 32 + i];
    float s0 = sn[s * 64 + i], s1 = sn[s * 64 + 32 + i];
    float lo = p[0], hi = p[32];
    p[0]  = lo * c0 - hi * s0;
    p[32] = hi * c1 + lo * s1;
  }
}

// ---------------------------------------------------------------------------
// fp32 flash attention with sink. BQ=128 q-rows per WG, BK=64 k-rows per tile.
// 256 threads. QK micro: 8 rows x 4 cols; PV micro: 8 rows x 8 cols.
// rows r = ty + 16*dr, score cols c = tx + 16*dc, out cols dv = tx*4(+64).
// Sink enters only the denominator: out = acc / (l + exp(sink - m)).
// LDS: Qs 66KiB + Vs 33KiB + union(K-tile, P) 34KiB = 133KiB -> 1 WG/CU.
// ---------------------------------------------------------------------------
__global__ __launch_bounds__(256) void attn_kernel(
    const float* __restrict__ Qb, const float* __restrict__ Kb,
    const float* __restrict__ Vb, const float* __restrict__ sink,
    float* __restrict__ Ob) {
  __shared__ float Qs[128 * 132];
  __shared__ float Vs[64 * 132];
  __shared__ float KP[128 * 68];   // union: K-tile [64][132] <=> P [128][68]

  const int tid = threadIdx.x;
  const int tx = tid & 15, ty = tid >> 4;
  const int h = blockIdx.y;
  const int qt = 15 - blockIdx.x;       // heaviest q-tiles first
  const int hk = h >> 2;                // GQA: 4 q-heads per kv-head
  const int q0 = qt * 128;

  // Stage the 128x128 Q tile once.
#pragma unroll
  for (int l = 0; l < 16; ++l) {
    int f = tid + 256 * l;              // 0..4095
    int row = f >> 5;
    int d4 = (f & 31) << 2;
    *reinterpret_cast<float4*>(&Qs[row * 132 + d4]) =
        *reinterpret_cast<const float4*>(
            &Qb[(size_t)(q0 + row) * (NH * HD) + h * HD + d4]);
  }

  float m[8], l_[8], acc[8][8];
#pragma unroll
  for (int i = 0; i < 8; ++i) {
    m[i] = NEG_INF;
    l_[i] = 0.f;
#pragma unroll
    for (int j = 0; j < 8; ++j) acc[i][j] = 0.f;
  }

  const int ntiles = 2 * qt + 2;
  for (int kt = 0; kt < ntiles; ++kt) {
    // Stage K and V tiles (64 x 128 each).
#pragma unroll
    for (int l = 0; l < 8; ++l) {
      int f = tid + 256 * l;            // 0..2047
      int row = f >> 5;                 // 0..63
      int d4 = (f & 31) << 2;
      size_t g = (size_t)(kt * 64 + row) * (NHK * HD) + hk * HD + d4;
      *reinterpret_cast<float4*>(&KP[row * 132 + d4]) =
          *reinterpret_cast<const float4*>(&Kb[g]);
      *reinterpret_cast<float4*>(&Vs[row * 132 + d4]) =
          *reinterpret_cast<const float4*>(&Vb[g]);
    }
    __syncthreads();

    // scores = Q . K^T
    float sc[8][4];
#pragma unroll
    for (int dr = 0; dr < 8; ++dr)
#pragma unroll
      for (int dc = 0; dc < 4; ++dc) sc[dr][dc] = 0.f;

    for (int d4 = 0; d4 < 32; ++d4) {
      float4 kf[4];
#pragma unroll
      for (int dc = 0; dc < 4; ++dc)
        kf[dc] = *reinterpret_cast<const float4*>(
            &KP[(tx + 16 * dc) * 132 + 4 * d4]);
#pragma unroll
      for (int dr = 0; dr < 8; ++dr) {
        float4 qf = *reinterpret_cast<const float4*>(
            &Qs[(ty + 16 * dr) * 132 + 4 * d4]);
#pragma unroll
        for (int dc = 0; dc < 4; ++dc) {
          sc[dr][dc] = fmaf(qf.x, kf[dc].x, sc[dr][dc]);
          sc[dr][dc] = fmaf(qf.y, kf[dc].y, sc[dr][dc]);
          sc[dr][dc] = fmaf(qf.z, kf[dc].z, sc[dr][dc]);
          sc[dr][dc] = fmaf(qf.w, kf[dc].w, sc[dr][dc]);
        }
      }
    }
    __syncthreads();   // all waves done reading K-tile (KP becomes P)

    // Online softmax update; write P to LDS.
#pragma unroll
    for (int dr = 0; dr < 8; ++dr) {
      int qrow = q0 + ty + 16 * dr;
      float tmax = NEG_INF;
#pragma unroll
      for (int dc = 0; dc < 4; ++dc) {
        int kcol = kt * 64 + tx + 16 * dc;
        sc[dr][dc] = (kcol <= qrow) ? sc[dr][dc] * ATT_SCALE : NEG_INF;
        tmax = fmaxf(tmax, sc[dr][dc]);
      }
#pragma unroll
      for (int off = 1; off < 16; off <<= 1)
        tmax = fmaxf(tmax, __shfl_xor(tmax, off));
      float mn = fmaxf(m[dr], tmax);
      float fac = __expf(m[dr] - mn);
      float rs = 0.f;
#pragma unroll
      for (int dc = 0; dc < 4; ++dc) {
        float p = __expf(sc[dr][dc] - mn);
        sc[dr][dc] = p;
        rs += p;
      }
#pragma unroll
      for (int off = 1; off < 16; off <<= 1)
        rs += __shfl_xor(rs, off);
      l_[dr] = l_[dr] * fac + rs;
      m[dr] = mn;
#pragma unroll
      for (int j = 0; j < 8; ++j) acc[dr][j] *= fac;
#pragma unroll
      for (int dc = 0; dc < 4; ++dc)
        KP[(ty + 16 * dr) * 68 + tx + 16 * dc] = sc[dr][dc];
    }
    __syncthreads();   // P visible to all

    // acc += P @ V
    for (int c4 = 0; c4 < 16; ++c4) {
      float4 pf[8];
#pragma unroll
      for (int dr = 0; dr < 8; ++dr)
        pf[dr] = *reinterpret_cast<const float4*>(
            &KP[(ty + 16 * dr) * 68 + 4 * c4]);
#pragma unroll
      for (int cc = 0; cc < 4; ++cc) {
        const float4 va = *reinterpret_cast<const float4*>(
            &Vs[(c4 * 4 + cc) * 132 + tx * 4]);
        const float4 vb = *reinterpret_cast<const float4*>(
            &Vs[(c4 * 4 + cc) * 132 + 64 + tx * 4]);
#pragma unroll
        for (int dr = 0; dr < 8; ++dr) {
          float p = (cc == 0) ? pf[dr].x : (cc == 1) ? pf[dr].y
                  : (cc == 2) ? pf[dr].z : pf[dr].w;
          acc[dr][0] = fmaf(p, va.x, acc[dr][0]);
          acc[dr][1] = fmaf(p, va.y, acc[dr][1]);
          acc[dr][2] = fmaf(p, va.z, acc[dr][2]);
          acc[dr][3] = fmaf(p, va.w, acc[dr][3]);
          acc[dr][4] = fmaf(p, vb.x, acc[dr][4]);
          acc[dr][5] = fmaf(p, vb.y, acc[dr][5]);
          acc[dr][6] = fmaf(p, vb.z, acc[dr][6]);
          acc[dr][7] = fmaf(p, vb.w, acc[dr][7]);
        }
      }
    }
    __syncthreads();   // done with P and Vs before next tile overwrites
  }

  // Epilogue: sink joins the denominator only.
  const float snk = sink[h];
#pragma unroll
  for (int dr = 0; dr < 8; ++dr) {
    float inv = 1.0f / (l_[dr] + __expf(snk - m[dr]));
    int r = q0 + ty + 16 * dr;
    float4 o0 = make_float4(acc[dr][0] * inv, acc[dr][1] * inv,
                            acc[dr][2] * inv, acc[dr][3] * inv);
    float4 o1 = make_float4(acc[dr][4] * inv, acc[dr][5] * inv,
                            acc[dr][6] * inv, acc[dr][7] * inv);
    *reinterpret_cast<float4*>(&Ob[(size_t)r * (NH * HD) + h * HD + tx * 4]) = o0;
    *reinterpret_cast<float4*>(
        &Ob[(size_t)r * (NH * HD) + h * HD + 64 + tx * 4]) = o1;
  }
}

// ---------------------------------------------------------------------------
extern "C" void kernel_launch(void* const* d_in, const int* in_sizes, int n_in,
                              void* d_out, int out_size, void* d_ws,
                              size_t ws_size, hipStream_t stream) {
  const float* hs   = (const float*)d_in[0];
  const float* cosb = (const float*)d_in[1];
  const float* sinb = (const float*)d_in[2];
  const float* Wq   = (const float*)d_in[3];
  const float* Wk   = (const float*)d_in[4];
  const float* Wv   = (const float*)d_in[5];
  const float* Wo   = (const float*)d_in[6];
  const float* sink = (const float*)d_in[7];
  float* out = (float*)d_out;

  float* Qb = (float*)d_ws;                        // 2048 x 2048
  float* Kb = Qb + (size_t)S_LEN * (NH * HD);      // 2048 x 512
  float* Vb = Kb + (size_t)S_LEN * (NHK * HD);     // 2048 x 512
  float* Ob = Vb + (size_t)S_LEN * (NHK * HD);     // 2048 x 2048

  qkv_proj_kernel<<<dim3(24, 16), 256, 0, stream>>>(hs, Wq, Wk, Wv, Qb, Kb, Vb);
  rope_kernel<<<dim3(5120), 256, 0, stream>>>(Qb, Kb, cosb, sinb);
  attn_kernel<<<dim3(16, 16), 256, 0, stream>>>(Qb, Kb, Vb, sink, Ob);
  out_proj_kernel<<<dim3(16, 16), 256, 0, stream>>>(Ob, Wo, out);
}

// Round 3
// 618.632 us; speedup vs baseline: 1.9859x; 1.9859x over previous
//
#include <hip/hip_runtime.h>

#define S_LEN 2048
#define HID_D 2048
#define NH 16
#define NHK 4
#define HD 128
#define ATT_SCALE 0.08838834764831845f   // 128^-0.5
#define NEG_INF (-3.0e38f)

typedef __attribute__((ext_vector_type(8))) __bf16 bf16x8;
typedef __attribute__((ext_vector_type(4))) __bf16 bf16x4;
typedef __attribute__((ext_vector_type(4))) float f32x4;

// ---------------------------------------------------------------------------
// fp32 -> bf16 elementwise (hidden states)
// ---------------------------------------------------------------------------
__global__ __launch_bounds__(256) void f32_to_bf16_kernel(
    const float* __restrict__ in, __bf16* __restrict__ out, int n4) {
  int i = blockIdx.x * 256 + threadIdx.x;
  if (i < n4) {
    float4 v = *reinterpret_cast<const float4*>(&in[(size_t)i * 4]);
    bf16x4 o;
    o[0] = (__bf16)v.x; o[1] = (__bf16)v.y; o[2] = (__bf16)v.z; o[3] = (__bf16)v.w;
    *reinterpret_cast<bf16x4*>(&out[(size_t)i * 4]) = o;
  }
}

// ---------------------------------------------------------------------------
// W [K][N] fp32 -> WT [N][K] bf16 (transpose during convert). 64x64 tiles.
// ---------------------------------------------------------------------------
__global__ __launch_bounds__(256) void transpose_f32_to_bf16(
    const float* __restrict__ W, __bf16* __restrict__ WT, int K, int N) {
  __shared__ float Ts[64][68];
  const int t = threadIdx.x;
  const int bk = blockIdx.y * 64, bn = blockIdx.x * 64;
  const int r = t >> 4, c4 = (t & 15) << 2;
#pragma unroll
  for (int i = 0; i < 4; ++i) {
    float4 v = *reinterpret_cast<const float4*>(
        &W[(size_t)(bk + r + 16 * i) * N + bn + c4]);
    *reinterpret_cast<float4*>(&Ts[r + 16 * i][c4]) = v;
  }
  __syncthreads();
#pragma unroll
  for (int i = 0; i < 4; ++i) {
    int n_l = r + 16 * i;
    bf16x4 o;
#pragma unroll
    for (int j = 0; j < 4; ++j) o[j] = (__bf16)Ts[c4 + j][n_l];
    *reinterpret_cast<bf16x4*>(&WT[(size_t)(bn + n_l) * K + bk + c4]) = o;
  }
}

// ---------------------------------------------------------------------------
// MFMA bf16 GEMM: C[M,N] fp32 = A[M,K] bf16 (row-major) @ BT[N,K] bf16.
// 128x128 tile, BK=64, 256 threads = 4 waves (2x2 quadrants of 64x64),
// 4x4 fragments of mfma_f32_16x16x32_bf16 per wave.
// Staging via global_load_lds width=16 into linear LDS (m97 structure).
// ---------------------------------------------------------------------------
__device__ __forceinline__ void gload_lds16(const void* g, void* l) {
  __builtin_amdgcn_global_load_lds(
      (__attribute__((address_space(1))) void*)g,
      (__attribute__((address_space(3))) void*)l, 16, 0, 0);
}

__device__ __forceinline__ void mfma_gemm_tile(
    const __bf16* __restrict__ A, const __bf16* __restrict__ BT,
    float* __restrict__ C, int N, int K, int bm, int bn) {
  __shared__ __attribute__((aligned(16))) __bf16 As[128 * 64];
  __shared__ __attribute__((aligned(16))) __bf16 Bs[128 * 64];
  const int tid = threadIdx.x;
  const int wave = tid >> 6, lane = tid & 63;
  const int wr = (wave >> 1) * 64, wc = (wave & 1) * 64;
  const int l16 = lane & 15, lhi = lane >> 4;

  f32x4 acc[4][4];
#pragma unroll
  for (int i = 0; i < 4; ++i)
#pragma unroll
    for (int j = 0; j < 4; ++j) acc[i][j] = (f32x4){0.f, 0.f, 0.f, 0.f};

  const __bf16* Abase = A + (size_t)bm * K;
  const __bf16* Bbase = BT + (size_t)bn * K;

  for (int k0 = 0; k0 < K; k0 += 64) {
    // Stage A-tile 128x64 and B-tile 128x64 (16 KB each).
    // 16B chunk index f: row = f>>3, chunk = f&7. LDS dest wave-uniform base.
#pragma unroll
    for (int it = 0; it < 4; ++it) {
      int base = it * 256 + wave * 64;      // wave-uniform 16B-chunk index
      int f = base + lane;
      int row = f >> 3, ch = f & 7;
      gload_lds16(Abase + (size_t)row * K + k0 + ch * 8, As + base * 8);
      gload_lds16(Bbase + (size_t)row * K + k0 + ch * 8, Bs + base * 8);
    }
    __syncthreads();   // drains vmcnt; tiles visible

#pragma unroll
    for (int kk = 0; kk < 2; ++kk) {
      bf16x8 af[4], bfr[4];
#pragma unroll
      for (int i = 0; i < 4; ++i) {
        af[i] = *reinterpret_cast<const bf16x8*>(
            As + (wr + i * 16 + l16) * 64 + kk * 32 + lhi * 8);
        bfr[i] = *reinterpret_cast<const bf16x8*>(
            Bs + (wc + i * 16 + l16) * 64 + kk * 32 + lhi * 8);
      }
#pragma unroll
      for (int i = 0; i < 4; ++i)
#pragma unroll
        for (int j = 0; j < 4; ++j)
          acc[i][j] = __builtin_amdgcn_mfma_f32_16x16x32_bf16(
              af[i], bfr[j], acc[i][j], 0, 0, 0);
    }
    __syncthreads();   // all reads done before next-tile overwrite
  }

  // C/D layout (m89-verified): col = lane&15, row = (lane>>4)*4 + reg.
#pragma unroll
  for (int i = 0; i < 4; ++i)
#pragma unroll
    for (int j = 0; j < 4; ++j) {
#pragma unroll
      for (int r = 0; r < 4; ++r) {
        int row = bm + wr + i * 16 + lhi * 4 + r;
        int col = bn + wc + j * 16 + l16;
        C[(size_t)row * N + col] = acc[i][j][r];
      }
    }
}

__global__ __launch_bounds__(256) void qkv_gemm_kernel(
    const __bf16* __restrict__ hsb, const __bf16* __restrict__ WqT,
    const __bf16* __restrict__ WkT, const __bf16* __restrict__ WvT,
    float* __restrict__ Qb, float* __restrict__ Kb, float* __restrict__ Vb) {
  const int bx = blockIdx.x;
  const int bm = blockIdx.y * 128;
  const __bf16* BT;
  float* Cp;
  int N, bn;
  if (bx < 16)      { BT = WqT; Cp = Qb; N = 2048; bn = bx * 128; }
  else if (bx < 20) { BT = WkT; Cp = Kb; N = 512;  bn = (bx - 16) * 128; }
  else              { BT = WvT; Cp = Vb; N = 512;  bn = (bx - 20) * 128; }
  mfma_gemm_tile(hsb, BT, Cp, N, HID_D, bm, bn);
}

__global__ __launch_bounds__(256) void out_proj_kernel(
    const __bf16* __restrict__ Obf, const __bf16* __restrict__ WoT,
    float* __restrict__ out) {
  mfma_gemm_tile(Obf, WoT, out, HID_D, NH * HD, blockIdx.y * 128,
                 blockIdx.x * 128);
}

// ---------------------------------------------------------------------------
// In-place RoPE on first 64 dims of each head (fp32 Q/K). Proven in round 1.
// ---------------------------------------------------------------------------
__global__ __launch_bounds__(256) void rope_kernel(
    float* __restrict__ Qb, float* __restrict__ Kb,
    const float* __restrict__ cs, const float* __restrict__ sn) {
  const int idx = blockIdx.x * 256 + threadIdx.x;
  const int QP = S_LEN * NH * 32;
  const int KP = S_LEN * NHK * 32;
  if (idx < QP) {
    int i = idx & 31;
    int h = (idx >> 5) & (NH - 1);
    int s = idx >> 9;
    float* p = Qb + (size_t)s * (NH * HD) + h * HD + i;
    float c0 = cs[s * 64 + i], c1 = cs[s * 64 + 32 + i];
    float s0 = sn[s * 64 + i], s1 = sn[s * 64 + 32 + i];
    float lo = p[0], hi = p[32];
    p[0]  = lo * c0 - hi * s0;
    p[32] = hi * c1 + lo * s1;
  } else if (idx < QP + KP) {
    int j = idx - QP;
    int i = j & 31;
    int hk = (j >> 5) & (NHK - 1);
    int s = j >> 7;
    float* p = Kb + (size_t)s * (NHK * HD) + hk * HD + i;
    float c0 = cs[s * 64 + i], c1 = cs[s * 64 + 32 + i];
    float s0 = sn[s * 64 + i], s1 = sn[s * 64 + 32 + i];
    float lo = p[0], hi = p[32];
    p[0]  = lo * c0 - hi * s0;
    p[32] = hi * c1 + lo * s1;
  }
}

// ---------------------------------------------------------------------------
// fp32 flash attention with sink, diagonal-pair balanced.
// BQ=64, BK=32, 512 threads (8 waves -> 2/SIMD). Block (p, h) processes
// q-tiles qt = 31-p then qt = p: every block does exactly 66 kv-tiles.
// Thread map: tx = tid&31 (score col / out col4), ty = tid>>5 (row group),
// rows = ty + 16*dr (dr 0..3). Writes Ob as bf16 for the Wo MFMA GEMM.
// LDS: Qs 33.8K + Vs 16.9K + union(K, P[64][36]) 16.9K = 67.6 KiB.
// ---------------------------------------------------------------------------
__global__ __launch_bounds__(512) void attn_kernel(
    const float* __restrict__ Qb, const float* __restrict__ Kb,
    const float* __restrict__ Vb, const float* __restrict__ sink,
    __bf16* __restrict__ Ob) {
  __shared__ float Qs[64 * 132];
  __shared__ float Vs[32 * 132];
  __shared__ float KP[32 * 132];   // union: K-tile [32][132] <=> P [64][36]
  float* Pp = KP;

  const int tid = threadIdx.x;
  const int tx = tid & 31, ty = tid >> 5;
  const int h = blockIdx.y;
  const int hk = h >> 2;
  const float snk = sink[h];

  for (int half = 0; half < 2; ++half) {
    const int qt = half ? blockIdx.x : (31 - blockIdx.x);
    const int q0 = qt * 64;

    // Stage Q tile 64 x 128.
#pragma unroll
    for (int l = 0; l < 4; ++l) {
      int f = tid + 512 * l;
      int row = f >> 5, d4 = (f & 31) << 2;
      *reinterpret_cast<float4*>(&Qs[row * 132 + d4]) =
          *reinterpret_cast<const float4*>(
              &Qb[(size_t)(q0 + row) * (NH * HD) + h * HD + d4]);
    }

    float m[4], l_[4], acc[4][4];
#pragma unroll
    for (int i = 0; i < 4; ++i) {
      m[i] = NEG_INF;
      l_[i] = 0.f;
#pragma unroll
      for (int j = 0; j < 4; ++j) acc[i][j] = 0.f;
    }

    const int nt = 2 * qt + 2;
    for (int kt = 0; kt < nt; ++kt) {
      __syncthreads();   // prev-iter LDS reads done (and Q staged, 1st iter)
      // Stage K and V tiles (32 x 128 each).
#pragma unroll
      for (int l = 0; l < 2; ++l) {
        int f = tid + 512 * l;
        int row = f >> 5, d4 = (f & 31) << 2;
        size_t g = (size_t)(kt * 32 + row) * (NHK * HD) + hk * HD + d4;
        *reinterpret_cast<float4*>(&KP[row * 132 + d4]) =
            *reinterpret_cast<const float4*>(&Kb[g]);
        *reinterpret_cast<float4*>(&Vs[row * 132 + d4]) =
            *reinterpret_cast<const float4*>(&Vb[g]);
      }
      __syncthreads();

      // scores = Q . K^T  (each thread: 4 rows x 1 col)
      float sc[4] = {0.f, 0.f, 0.f, 0.f};
      for (int d4 = 0; d4 < 32; ++d4) {
        float4 kf = *reinterpret_cast<const float4*>(&KP[tx * 132 + 4 * d4]);
#pragma unroll
        for (int dr = 0; dr < 4; ++dr) {
          float4 qf = *reinterpret_cast<const float4*>(
              &Qs[(ty + 16 * dr) * 132 + 4 * d4]);
          sc[dr] = fmaf(qf.x, kf.x, sc[dr]);
          sc[dr] = fmaf(qf.y, kf.y, sc[dr]);
          sc[dr] = fmaf(qf.z, kf.z, sc[dr]);
          sc[dr] = fmaf(qf.w, kf.w, sc[dr]);
        }
      }
      __syncthreads();   // done reading K (KP becomes P)

      // Online softmax; write P.
#pragma unroll
      for (int dr = 0; dr < 4; ++dr) {
        int qrow = q0 + ty + 16 * dr;
        int kcol = kt * 32 + tx;
        float s = (kcol <= qrow) ? sc[dr] * ATT_SCALE : NEG_INF;
        float tmax = s;
#pragma unroll
        for (int off = 1; off < 32; off <<= 1)
          tmax = fmaxf(tmax, __shfl_xor(tmax, off));
        float mn = fmaxf(m[dr], tmax);
        float fac = __expf(m[dr] - mn);
        float p = __expf(s - mn);
        float rs = p;
#pragma unroll
        for (int off = 1; off < 32; off <<= 1) rs += __shfl_xor(rs, off);
        l_[dr] = l_[dr] * fac + rs;
        m[dr] = mn;
#pragma unroll
        for (int j = 0; j < 4; ++j) acc[dr][j] *= fac;
        Pp[(ty + 16 * dr) * 36 + tx] = p;
      }
      __syncthreads();   // P visible

      // acc += P @ V  (each thread: 4 rows x 4 out cols at tx*4)
      for (int c4 = 0; c4 < 8; ++c4) {
        float4 pf[4];
#pragma unroll
        for (int dr = 0; dr < 4; ++dr)
          pf[dr] = *reinterpret_cast<const float4*>(
              &Pp[(ty + 16 * dr) * 36 + c4 * 4]);
#pragma unroll
        for (int cc = 0; cc < 4; ++cc) {
          const float4 vv = *reinterpret_cast<const float4*>(
              &Vs[(c4 * 4 + cc) * 132 + tx * 4]);
#pragma unroll
          for (int dr = 0; dr < 4; ++dr) {
            float p = (cc == 0) ? pf[dr].x : (cc == 1) ? pf[dr].y
                    : (cc == 2) ? pf[dr].z : pf[dr].w;
            acc[dr][0] = fmaf(p, vv.x, acc[dr][0]);
            acc[dr][1] = fmaf(p, vv.y, acc[dr][1]);
            acc[dr][2] = fmaf(p, vv.z, acc[dr][2]);
            acc[dr][3] = fmaf(p, vv.w, acc[dr][3]);
          }
        }
      }
      // loop-top __syncthreads guards the KP/Vs overwrite
    }

    // Epilogue: sink joins denominator only; write bf16 for Wo GEMM.
#pragma unroll
    for (int dr = 0; dr < 4; ++dr) {
      float inv = 1.0f / (l_[dr] + __expf(snk - m[dr]));
      int r = q0 + ty + 16 * dr;
      bf16x4 o;
#pragma unroll
      for (int j = 0; j < 4; ++j) o[j] = (__bf16)(acc[dr][j] * inv);
      *reinterpret_cast<bf16x4*>(
          &Ob[(size_t)r * (NH * HD) + h * HD + tx * 4]) = o;
    }
  }
}

// ---------------------------------------------------------------------------
extern "C" void kernel_launch(void* const* d_in, const int* in_sizes, int n_in,
                              void* d_out, int out_size, void* d_ws,
                              size_t ws_size, hipStream_t stream) {
  const float* hs   = (const float*)d_in[0];
  const float* cosb = (const float*)d_in[1];
  const float* sinb = (const float*)d_in[2];
  const float* Wq   = (const float*)d_in[3];
  const float* Wk   = (const float*)d_in[4];
  const float* Wv   = (const float*)d_in[5];
  const float* Wo   = (const float*)d_in[6];
  const float* sink = (const float*)d_in[7];
  float* out = (float*)d_out;

  // Workspace layout (52 MB):
  float* Qb = (float*)d_ws;                            // 4M f32
  float* Kb = Qb + (size_t)S_LEN * (NH * HD);          // 1M f32
  float* Vb = Kb + (size_t)S_LEN * (NHK * HD);         // 1M f32
  __bf16* hsb = (__bf16*)(Vb + (size_t)S_LEN * (NHK * HD));  // 4M bf16
  __bf16* WqT = hsb + (size_t)S_LEN * HID_D;           // 4M bf16
  __bf16* WkT = WqT + (size_t)HID_D * (NH * HD);       // 1M bf16
  __bf16* WvT = WkT + (size_t)HID_D * (NHK * HD);      // 1M bf16
  __bf16* WoT = WvT + (size_t)HID_D * (NHK * HD);      // 4M bf16
  __bf16* Obf = WqT;   // alias: WqT is dead after qkv_gemm

  // Conversions.
  f32_to_bf16_kernel<<<dim3(4096), 256, 0, stream>>>(hs, hsb,
                                                     S_LEN * HID_D / 4);
  transpose_f32_to_bf16<<<dim3(32, 32), 256, 0, stream>>>(Wq, WqT, HID_D, 2048);
  transpose_f32_to_bf16<<<dim3(8, 32), 256, 0, stream>>>(Wk, WkT, HID_D, 512);
  transpose_f32_to_bf16<<<dim3(8, 32), 256, 0, stream>>>(Wv, WvT, HID_D, 512);
  transpose_f32_to_bf16<<<dim3(32, 32), 256, 0, stream>>>(Wo, WoT, 2048, 2048);

  qkv_gemm_kernel<<<dim3(24, 16), 256, 0, stream>>>(hsb, WqT, WkT, WvT,
                                                    Qb, Kb, Vb);
  rope_kernel<<<dim3(5120), 256, 0, stream>>>(Qb, Kb, cosb, sinb);
  attn_kernel<<<dim3(16, 16), 512, 0, stream>>>(Qb, Kb, Vb, sink, Obf);
  out_proj_kernel<<<dim3(16, 16), 256, 0, stream>>>(Obf, WoT, out);
}

// Round 5
// 277.217 us; speedup vs baseline: 4.4318x; 2.2316x over previous
//
#include <hip/hip_runtime.h>

#define S_LEN 2048
#define HID_D 2048
#define NH 16
#define NHK 4
#define HD 128
#define ATT_SCALE 0.08838834764831845f   // 128^-0.5
#define NEG_INF (-3.0e38f)

typedef __attribute__((ext_vector_type(8))) __bf16 bf16x8;
typedef __attribute__((ext_vector_type(4))) __bf16 bf16x4;
typedef __attribute__((ext_vector_type(4))) float f32x4;

// ---------------------------------------------------------------------------
// fp32 -> bf16 elementwise (hidden states)
// ---------------------------------------------------------------------------
__global__ __launch_bounds__(256) void f32_to_bf16_kernel(
    const float* __restrict__ in, __bf16* __restrict__ out, int n4) {
  int i = blockIdx.x * 256 + threadIdx.x;
  if (i < n4) {
    float4 v = *reinterpret_cast<const float4*>(&in[(size_t)i * 4]);
    bf16x4 o;
    o[0] = (__bf16)v.x; o[1] = (__bf16)v.y; o[2] = (__bf16)v.z; o[3] = (__bf16)v.w;
    *reinterpret_cast<bf16x4*>(&out[(size_t)i * 4]) = o;
  }
}

// ---------------------------------------------------------------------------
// W [K][N] fp32 -> WT [N][K] bf16 (transpose during convert). 64x64 tiles.
// Also reused for V [S][512] -> Vt [512][S].
// ---------------------------------------------------------------------------
__global__ __launch_bounds__(256) void transpose_f32_to_bf16(
    const float* __restrict__ W, __bf16* __restrict__ WT, int K, int N) {
  __shared__ float Ts[64][68];
  const int t = threadIdx.x;
  const int bk = blockIdx.y * 64, bn = blockIdx.x * 64;
  const int r = t >> 4, c4 = (t & 15) << 2;
#pragma unroll
  for (int i = 0; i < 4; ++i) {
    float4 v = *reinterpret_cast<const float4*>(
        &W[(size_t)(bk + r + 16 * i) * N + bn + c4]);
    *reinterpret_cast<float4*>(&Ts[r + 16 * i][c4]) = v;
  }
  __syncthreads();
#pragma unroll
  for (int i = 0; i < 4; ++i) {
    int n_l = r + 16 * i;
    bf16x4 o;
#pragma unroll
    for (int j = 0; j < 4; ++j) o[j] = (__bf16)Ts[c4 + j][n_l];
    *reinterpret_cast<bf16x4*>(&WT[(size_t)(bn + n_l) * K + bk + c4]) = o;
  }
}

// ---------------------------------------------------------------------------
// MFMA bf16 GEMM (m97 structure), unchanged from round 3.
// ---------------------------------------------------------------------------
__device__ __forceinline__ void gload_lds16(const void* g, void* l) {
  __builtin_amdgcn_global_load_lds(
      (__attribute__((address_space(1))) void*)g,
      (__attribute__((address_space(3))) void*)l, 16, 0, 0);
}

__device__ __forceinline__ void mfma_gemm_tile(
    const __bf16* __restrict__ A, const __bf16* __restrict__ BT,
    float* __restrict__ C, int N, int K, int bm, int bn) {
  __shared__ __attribute__((aligned(16))) __bf16 As[128 * 64];
  __shared__ __attribute__((aligned(16))) __bf16 Bs[128 * 64];
  const int tid = threadIdx.x;
  const int wave = tid >> 6, lane = tid & 63;
  const int wr = (wave >> 1) * 64, wc = (wave & 1) * 64;
  const int l16 = lane & 15, lhi = lane >> 4;

  f32x4 acc[4][4];
#pragma unroll
  for (int i = 0; i < 4; ++i)
#pragma unroll
    for (int j = 0; j < 4; ++j) acc[i][j] = (f32x4){0.f, 0.f, 0.f, 0.f};

  const __bf16* Abase = A + (size_t)bm * K;
  const __bf16* Bbase = BT + (size_t)bn * K;

  for (int k0 = 0; k0 < K; k0 += 64) {
#pragma unroll
    for (int it = 0; it < 4; ++it) {
      int base = it * 256 + wave * 64;
      int f = base + lane;
      int row = f >> 3, ch = f & 7;
      gload_lds16(Abase + (size_t)row * K + k0 + ch * 8, As + base * 8);
      gload_lds16(Bbase + (size_t)row * K + k0 + ch * 8, Bs + base * 8);
    }
    __syncthreads();

#pragma unroll
    for (int kk = 0; kk < 2; ++kk) {
      bf16x8 af[4], bfr[4];
#pragma unroll
      for (int i = 0; i < 4; ++i) {
        af[i] = *reinterpret_cast<const bf16x8*>(
            As + (wr + i * 16 + l16) * 64 + kk * 32 + lhi * 8);
        bfr[i] = *reinterpret_cast<const bf16x8*>(
            Bs + (wc + i * 16 + l16) * 64 + kk * 32 + lhi * 8);
      }
#pragma unroll
      for (int i = 0; i < 4; ++i)
#pragma unroll
        for (int j = 0; j < 4; ++j)
          acc[i][j] = __builtin_amdgcn_mfma_f32_16x16x32_bf16(
              af[i], bfr[j], acc[i][j], 0, 0, 0);
    }
    __syncthreads();
  }

#pragma unroll
  for (int i = 0; i < 4; ++i)
#pragma unroll
    for (int j = 0; j < 4; ++j) {
#pragma unroll
      for (int r = 0; r < 4; ++r) {
        int row = bm + wr + i * 16 + lhi * 4 + r;
        int col = bn + wc + j * 16 + l16;
        C[(size_t)row * N + col] = acc[i][j][r];
      }
    }
}

__global__ __launch_bounds__(256) void qkv_gemm_kernel(
    const __bf16* __restrict__ hsb, const __bf16* __restrict__ WqT,
    const __bf16* __restrict__ WkT, const __bf16* __restrict__ WvT,
    float* __restrict__ Qb, float* __restrict__ Kb, float* __restrict__ Vb) {
  const int bx = blockIdx.x;
  const int bm = blockIdx.y * 128;
  const __bf16* BT;
  float* Cp;
  int N, bn;
  if (bx < 16)      { BT = WqT; Cp = Qb; N = 2048; bn = bx * 128; }
  else if (bx < 20) { BT = WkT; Cp = Kb; N = 512;  bn = (bx - 16) * 128; }
  else              { BT = WvT; Cp = Vb; N = 512;  bn = (bx - 20) * 128; }
  mfma_gemm_tile(hsb, BT, Cp, N, HID_D, bm, bn);
}

__global__ __launch_bounds__(256) void out_proj_kernel(
    const __bf16* __restrict__ Obf, const __bf16* __restrict__ WoT,
    float* __restrict__ out) {
  mfma_gemm_tile(Obf, WoT, out, HID_D, NH * HD, blockIdx.y * 128,
                 blockIdx.x * 128);
}

// ---------------------------------------------------------------------------
// Fused RoPE + fp32->bf16 pack for Q and K.
// Q: [S][2048] -> Qbf; K: [S][512] -> Kbf. RoPE on first 64 of each 128-slice.
// ---------------------------------------------------------------------------
__global__ __launch_bounds__(256) void rope_pack_kernel(
    const float* __restrict__ Qb, const float* __restrict__ Kb,
    const float* __restrict__ cs, const float* __restrict__ sn,
    __bf16* __restrict__ Qbf, __bf16* __restrict__ Kbf) {
  const int idx = blockIdx.x * 256 + threadIdx.x;
  const int QE = S_LEN * HID_D;            // 4M
  int e4 = idx * 4;
  const float* src;
  __bf16* dst;
  int s, col;
  if (e4 < QE) {
    s = e4 >> 11; col = e4 & 2047;
    src = Qb + (size_t)s * 2048; dst = Qbf + (size_t)s * 2048;
  } else {
    e4 -= QE;
    if (e4 >= S_LEN * 512) return;
    s = e4 >> 9; col = e4 & 511;
    src = Kb + (size_t)s * 512; dst = Kbf + (size_t)s * 512;
  }
  float4 v = *reinterpret_cast<const float4*>(&src[col]);
  int hc = col & 127;
  float o[4] = {v.x, v.y, v.z, v.w};
  if (hc < 64) {
    if (hc < 32) {
      float4 p = *reinterpret_cast<const float4*>(&src[col + 32]);
      float pp[4] = {p.x, p.y, p.z, p.w};
#pragma unroll
      for (int t = 0; t < 4; ++t) {
        int i = hc + t;
        o[t] = o[t] * cs[s * 64 + i] - pp[t] * sn[s * 64 + i];
      }
    } else {
      float4 p = *reinterpret_cast<const float4*>(&src[col - 32]);
      float pp[4] = {p.x, p.y, p.z, p.w};
#pragma unroll
      for (int t = 0; t < 4; ++t) {
        int i = hc + t;
        o[t] = o[t] * cs[s * 64 + i] + pp[t] * sn[s * 64 + i];
      }
    }
  }
  bf16x4 ob;
#pragma unroll
  for (int t = 0; t < 4; ++t) ob[t] = (__bf16)o[t];
  *reinterpret_cast<bf16x4*>(&dst[col]) = ob;
}

// ---------------------------------------------------------------------------
// MFMA bf16 flash attention with sink.
// Block: 256 thr (4 waves), head = blockIdx.y, q-tile BQ=64 (16 q-rows/wave),
// BK=64 k-rows per iteration. Swapped QK^T (mfma(K,Q)) so each lane owns one
// q-row's score strip; P redistributed to PV A-layout via lane shuffles.
// K LDS [64][256B] and Vt LDS [128][128B] XOR-swizzled (chunk ^= row&7) via
// pre-swizzled global source (global_load_lds writes linearly).
// ---------------------------------------------------------------------------
__device__ __forceinline__ unsigned pack2_bf16(float a, float b) {
  unsigned short lo = __builtin_bit_cast(unsigned short, (__bf16)a);
  unsigned short hi = __builtin_bit_cast(unsigned short, (__bf16)b);
  return (unsigned)lo | ((unsigned)hi << 16);
}

__global__ __launch_bounds__(256, 2) void attn_mfma_kernel(
    const __bf16* __restrict__ Qbf, const __bf16* __restrict__ Kbf,
    const __bf16* __restrict__ Vtb, const float* __restrict__ sink,
    __bf16* __restrict__ Obf) {
  __shared__ __attribute__((aligned(16))) __bf16 Ks[64 * 128];   // 16 KB
  __shared__ __attribute__((aligned(16))) __bf16 Vs[128 * 64];   // 16 KB

  const int tid = threadIdx.x;
  const int wave = tid >> 6, lane = tid & 63;
  const int l16 = lane & 15, lhi = lane >> 4;
  const int h = blockIdx.y;
  const int hk = h >> 2;
  const int qt = (h < 8) ? (31 - (int)blockIdx.x) : (int)blockIdx.x;
  const int q0 = qt * 64;
  const int qrow = q0 + wave * 16 + l16;   // this lane's q-row (score side)

  // Q B-fragments in registers: qf[d] = Q[qrow][d*32 + lhi*8 .. +7]
  bf16x8 qf[4];
  {
    const __bf16* qp = Qbf + (size_t)qrow * (NH * HD) + h * HD + lhi * 8;
#pragma unroll
    for (int d = 0; d < 4; ++d)
      qf[d] = *reinterpret_cast<const bf16x8*>(qp + d * 32);
  }

  float m = NEG_INF, l_ = 0.f;
  f32x4 acc[8];
#pragma unroll
  for (int f = 0; f < 8; ++f) acc[f] = (f32x4){0.f, 0.f, 0.f, 0.f};

  const int xs7 = l16 & 7;   // read-side swizzle key (row&7 == l16&7 here)
  const int nt = qt + 1;
  for (int kt = 0; kt < nt; ++kt) {
    // ---- stage K (64 rows x 16 chunks) and Vt (128 rows x 8 chunks) ----
#pragma unroll
    for (int it = 0; it < 4; ++it) {
      int base = it * 256 + wave * 64;     // wave-uniform chunk base
      int f = base + lane;
      {
        int row = f >> 4, ch = f & 15;
        int sch = (ch & 8) | ((ch ^ row) & 7);   // chunk ^ (row&7), low 3 bits
        gload_lds16(Kbf + (size_t)(kt * 64 + row) * (NHK * HD) + hk * HD +
                        sch * 8,
                    Ks + base * 8);
      }
      {
        int dv = f >> 3, ch = f & 7;
        int sch = (ch ^ dv) & 7;
        gload_lds16(Vtb + (size_t)(hk * HD + dv) * S_LEN + kt * 64 + sch * 8,
                    Vs + base * 8);
      }
    }
    __syncthreads();

    // ---- QK^T (swapped): sc[kb] over k-rows kb*16 + lhi*4 + r ----
    f32x4 sc[4];
#pragma unroll
    for (int kb = 0; kb < 4; ++kb) sc[kb] = (f32x4){0.f, 0.f, 0.f, 0.f};
#pragma unroll
    for (int d = 0; d < 4; ++d) {
#pragma unroll
      for (int kb = 0; kb < 4; ++kb) {
        int row = kb * 16 + l16;
        int ch = (d * 4 + lhi) ^ xs7;
        bf16x8 kf = *reinterpret_cast<const bf16x8*>(Ks + row * 128 + ch * 8);
        sc[kb] = __builtin_amdgcn_mfma_f32_16x16x32_bf16(kf, qf[d], sc[kb],
                                                         0, 0, 0);
      }
    }

    // ---- softmax (per-lane: 16 scores of one q-row) ----
    float s[4][4];
    const bool last = (kt == qt);
#pragma unroll
    for (int kb = 0; kb < 4; ++kb)
#pragma unroll
      for (int r = 0; r < 4; ++r) {
        float sv = sc[kb][r] * ATT_SCALE;
        if (last) {
          int kc = kt * 64 + kb * 16 + lhi * 4 + r;
          if (kc > qrow) sv = NEG_INF;
        }
        s[kb][r] = sv;
      }
    float tmax = s[0][0];
#pragma unroll
    for (int kb = 0; kb < 4; ++kb)
#pragma unroll
      for (int r = 0; r < 4; ++r) tmax = fmaxf(tmax, s[kb][r]);
    tmax = fmaxf(tmax, __shfl_xor(tmax, 16));
    tmax = fmaxf(tmax, __shfl_xor(tmax, 32));
    float mn = fmaxf(m, tmax);
    float fac = __expf(m - mn);
    m = mn;
    float p[4][4];
    float rs = 0.f;
#pragma unroll
    for (int kb = 0; kb < 4; ++kb)
#pragma unroll
      for (int r = 0; r < 4; ++r) {
        float pv = __expf(s[kb][r] - mn);
        p[kb][r] = pv;
        rs += pv;
      }
    rs += __shfl_xor(rs, 16);
    rs += __shfl_xor(rs, 32);
    l_ = l_ * fac + rs;

    // ---- rescale acc (acc rows are q-rows lhi*4+r) ----
    float facb[4];
#pragma unroll
    for (int r = 0; r < 4; ++r) facb[r] = __shfl(fac, lhi * 4 + r);
#pragma unroll
    for (int f = 0; f < 8; ++f)
#pragma unroll
      for (int r = 0; r < 4; ++r) acc[f][r] *= facb[r];

    // ---- pack P to bf16 pairs; redistribute to PV A-layout ----
    unsigned pk[4][2];
#pragma unroll
    for (int kb = 0; kb < 4; ++kb) {
      pk[kb][0] = pack2_bf16(p[kb][0], p[kb][1]);
      pk[kb][1] = pack2_bf16(p[kb][2], p[kb][3]);
    }
    const int s0 = l16 + 16 * (2 * (lhi & 1));
    const int s1 = s0 + 16;
    const bool hihalf = (lhi >= 2);
    bf16x8 pa[2];
#pragma unroll
    for (int c = 0; c < 2; ++c) {
      unsigned aw0 = __shfl((int)pk[2 * c][0], s0);
      unsigned aw1 = __shfl((int)pk[2 * c][1], s0);
      unsigned aw2 = __shfl((int)pk[2 * c][0], s1);
      unsigned aw3 = __shfl((int)pk[2 * c][1], s1);
      unsigned bw0 = __shfl((int)pk[2 * c + 1][0], s0);
      unsigned bw1 = __shfl((int)pk[2 * c + 1][1], s0);
      unsigned bw2 = __shfl((int)pk[2 * c + 1][0], s1);
      unsigned bw3 = __shfl((int)pk[2 * c + 1][1], s1);
      uint4 w;
      w.x = hihalf ? bw0 : aw0;
      w.y = hihalf ? bw1 : aw1;
      w.z = hihalf ? bw2 : aw2;
      w.w = hihalf ? bw3 : aw3;
      pa[c] = __builtin_bit_cast(bf16x8, w);
    }

    // ---- PV: acc[dvf] += pa[c] @ V[c-chunk][dvf*16 + l16] ----
#pragma unroll
    for (int c = 0; c < 2; ++c) {
#pragma unroll
      for (int dvf = 0; dvf < 8; ++dvf) {
        int row = dvf * 16 + l16;
        int ch = (c * 4 + lhi) ^ xs7;
        bf16x8 vf = *reinterpret_cast<const bf16x8*>(Vs + row * 64 + ch * 8);
        acc[dvf] = __builtin_amdgcn_mfma_f32_16x16x32_bf16(pa[c], vf, acc[dvf],
                                                           0, 0, 0);
      }
    }
    __syncthreads();   // all LDS reads done before next stage overwrites
  }

  // ---- epilogue: sink in denominator; store bf16 ----
  float inv = 1.0f / (l_ + __expf(sink[h] - m));   // for q-row l16
  float invb[4];
#pragma unroll
  for (int r = 0; r < 4; ++r) invb[r] = __shfl(inv, lhi * 4 + r);
#pragma unroll
  for (int dvf = 0; dvf < 8; ++dvf)
#pragma unroll
    for (int r = 0; r < 4; ++r) {
      int row = q0 + wave * 16 + lhi * 4 + r;
      Obf[(size_t)row * (NH * HD) + h * HD + dvf * 16 + l16] =
          (__bf16)(acc[dvf][r] * invb[r]);
    }
}

// ---------------------------------------------------------------------------
extern "C" void kernel_launch(void* const* d_in, const int* in_sizes, int n_in,
                              void* d_out, int out_size, void* d_ws,
                              size_t ws_size, hipStream_t stream) {
  const float* hs   = (const float*)d_in[0];
  const float* cosb = (const float*)d_in[1];
  const float* sinb = (const float*)d_in[2];
  const float* Wq   = (const float*)d_in[3];
  const float* Wk   = (const float*)d_in[4];
  const float* Wv   = (const float*)d_in[5];
  const float* Wo   = (const float*)d_in[6];
  const float* sink = (const float*)d_in[7];
  float* out = (float*)d_out;

  // Workspace layout (52 MB), with aliasing of buffers dead after qkv_gemm.
  float* Qb = (float*)d_ws;                            // 4M f32
  float* Kb = Qb + (size_t)S_LEN * (NH * HD);          // 1M f32
  float* Vb = Kb + (size_t)S_LEN * (NHK * HD);         // 1M f32
  __bf16* hsb = (__bf16*)(Vb + (size_t)S_LEN * (NHK * HD));  // 4M bf16
  __bf16* WqT = hsb + (size_t)S_LEN * HID_D;           // 4M bf16
  __bf16* WkT = WqT + (size_t)HID_D * (NH * HD);       // 1M bf16
  __bf16* WvT = WkT + (size_t)HID_D * (NHK * HD);      // 1M bf16
  __bf16* WoT = WvT + (size_t)HID_D * (NHK * HD);      // 4M bf16
  __bf16* Qbf = hsb;   // alias: hsb dead after qkv_gemm
  __bf16* Kbf = WkT;   // alias: WkT dead after qkv_gemm
  __bf16* Vtb = WvT;   // alias: WvT dead after qkv_gemm
  __bf16* Obf = WqT;   // alias: WqT dead after qkv_gemm

  f32_to_bf16_kernel<<<dim3(4096), 256, 0, stream>>>(hs, hsb,
                                                     S_LEN * HID_D / 4);
  transpose_f32_to_bf16<<<dim3(32, 32), 256, 0, stream>>>(Wq, WqT, HID_D, 2048);
  transpose_f32_to_bf16<<<dim3(8, 32), 256, 0, stream>>>(Wk, WkT, HID_D, 512);
  transpose_f32_to_bf16<<<dim3(8, 32), 256, 0, stream>>>(Wv, WvT, HID_D, 512);
  transpose_f32_to_bf16<<<dim3(32, 32), 256, 0, stream>>>(Wo, WoT, 2048, 2048);

  qkv_gemm_kernel<<<dim3(24, 16), 256, 0, stream>>>(hsb, WqT, WkT, WvT,
                                                    Qb, Kb, Vb);

  // RoPE + pack Q/K to bf16 (5M elems / 4 per thread).
  rope_pack_kernel<<<dim3(5120), 256, 0, stream>>>(Qb, Kb, cosb, sinb,
                                                   Qbf, Kbf);
  // V [S][512] f32 -> Vt [512][S] bf16.
  transpose_f32_to_bf16<<<dim3(8, 32), 256, 0, stream>>>(Vb, Vtb, S_LEN, 512);

  attn_mfma_kernel<<<dim3(32, 16), 256, 0, stream>>>(Qbf, Kbf, Vtb, sink, Obf);
  out_proj_kernel<<<dim3(16, 16), 256, 0, stream>>>(Obf, WoT, out);
}

// Round 6
// 274.782 us; speedup vs baseline: 4.4711x; 1.0089x over previous
//
#include <hip/hip_runtime.h>

#define S_LEN 2048
#define HID_D 2048
#define NH 16
#define NHK 4
#define HD 128
#define ATT_SCALE 0.08838834764831845f   // 128^-0.5
#define NEG_INF (-3.0e38f)

typedef __attribute__((ext_vector_type(8))) __bf16 bf16x8;
typedef __attribute__((ext_vector_type(4))) __bf16 bf16x4;
typedef __attribute__((ext_vector_type(4))) float f32x4;

__device__ __forceinline__ void gload_lds16(const void* g, void* l) {
  __builtin_amdgcn_global_load_lds(
      (__attribute__((address_space(1))) void*)g,
      (__attribute__((address_space(3))) void*)l, 16, 0, 0);
}

// ---------------------------------------------------------------------------
// prep: hs f32->bf16 (blocks 0..4095) + 4 weight transposes (blocks 4096..6655)
// ---------------------------------------------------------------------------
__device__ __forceinline__ void transpose_job(
    const float* __restrict__ W, __bf16* __restrict__ WT, int K, int N,
    int local, int nbx, float* Ts /*[64*68]*/) {
  const int t = threadIdx.x;
  const int bk = (local / nbx) * 64, bn = (local % nbx) * 64;
  const int r = t >> 4, c4 = (t & 15) << 2;
#pragma unroll
  for (int i = 0; i < 4; ++i) {
    float4 v = *reinterpret_cast<const float4*>(
        &W[(size_t)(bk + r + 16 * i) * N + bn + c4]);
    *reinterpret_cast<float4*>(&Ts[(r + 16 * i) * 68 + c4]) = v;
  }
  __syncthreads();
#pragma unroll
  for (int i = 0; i < 4; ++i) {
    int n_l = r + 16 * i;
    bf16x4 o;
#pragma unroll
    for (int j = 0; j < 4; ++j) o[j] = (__bf16)Ts[(c4 + j) * 68 + n_l];
    *reinterpret_cast<bf16x4*>(&WT[(size_t)(bn + n_l) * K + bk + c4]) = o;
  }
}

__global__ __launch_bounds__(256) void prep_kernel(
    const float* __restrict__ hs, const float* __restrict__ Wq,
    const float* __restrict__ Wk, const float* __restrict__ Wv,
    const float* __restrict__ Wo, __bf16* __restrict__ hsb,
    __bf16* __restrict__ WqT, __bf16* __restrict__ WkT,
    __bf16* __restrict__ WvT, __bf16* __restrict__ WoT) {
  __shared__ float Ts[64 * 68];
  const int b = blockIdx.x;
  if (b < 4096) {
    int i = b * 256 + threadIdx.x;
    if (i < S_LEN * HID_D / 4) {
      float4 v = *reinterpret_cast<const float4*>(&hs[(size_t)i * 4]);
      bf16x4 o;
      o[0] = (__bf16)v.x; o[1] = (__bf16)v.y;
      o[2] = (__bf16)v.z; o[3] = (__bf16)v.w;
      *reinterpret_cast<bf16x4*>(&hsb[(size_t)i * 4]) = o;
    }
  } else if (b < 5120) {
    transpose_job(Wq, WqT, 2048, 2048, b - 4096, 32, Ts);
  } else if (b < 5376) {
    transpose_job(Wk, WkT, 2048, 512, b - 5120, 8, Ts);
  } else if (b < 5632) {
    transpose_job(Wv, WvT, 2048, 512, b - 5376, 8, Ts);
  } else {
    transpose_job(Wo, WoT, 2048, 2048, b - 5632, 32, Ts);
  }
}

// ---------------------------------------------------------------------------
// Double-buffered MFMA bf16 GEMM tile. 128x128, BK=64, 4 waves (2x2 quads).
// STAGE(next) issued BEFORE compute(cur); one __syncthreads per k-step
// (its vmcnt(0) drain waits on loads that had the whole compute to land).
// MODE 0: fp32 C store. MODE 1/2: bf16 + fused RoPE (Q stride 2048 / K 512).
// MODE 3: bf16 transposed store (V^T [512][S]).
// ---------------------------------------------------------------------------
template <int MODE>
__device__ __forceinline__ void mfma_gemm_tile_db(
    __bf16* As, __bf16* Bs,   // LDS, [2*8192] each
    const __bf16* __restrict__ A, const __bf16* __restrict__ BT,
    float* __restrict__ C, __bf16* __restrict__ Db,
    const float* __restrict__ cs, const float* __restrict__ sn,
    int N, int K, int bm, int bn) {
  const int tid = threadIdx.x;
  const int wave = tid >> 6, lane = tid & 63;
  const int wr = (wave >> 1) * 64, wc = (wave & 1) * 64;
  const int l16 = lane & 15, lhi = lane >> 4;

  f32x4 acc[4][4];
#pragma unroll
  for (int i = 0; i < 4; ++i)
#pragma unroll
    for (int j = 0; j < 4; ++j) acc[i][j] = (f32x4){0.f, 0.f, 0.f, 0.f};

  const __bf16* Abase = A + (size_t)bm * K;
  const __bf16* Bbase = BT + (size_t)bn * K;
  const int nk = K >> 6;

  auto stage = [&](int buf, int k0) {
#pragma unroll
    for (int it = 0; it < 4; ++it) {
      int base = it * 256 + wave * 64;   // wave-uniform 16B-chunk index
      int f = base + lane;
      int row = f >> 3, ch = f & 7;
      gload_lds16(Abase + (size_t)row * K + k0 + ch * 8,
                  As + buf * 8192 + base * 8);
      gload_lds16(Bbase + (size_t)row * K + k0 + ch * 8,
                  Bs + buf * 8192 + base * 8);
    }
  };

  stage(0, 0);
  __syncthreads();
  for (int t = 0; t < nk; ++t) {
    const int buf = t & 1;
    if (t + 1 < nk) stage(buf ^ 1, (t + 1) * 64);   // overlap with compute
    const __bf16* Ab = As + buf * 8192;
    const __bf16* Bb = Bs + buf * 8192;
#pragma unroll
    for (int kk = 0; kk < 2; ++kk) {
      bf16x8 af[4], bfr[4];
#pragma unroll
      for (int i = 0; i < 4; ++i) {
        af[i] = *reinterpret_cast<const bf16x8*>(
            Ab + (wr + i * 16 + l16) * 64 + kk * 32 + lhi * 8);
        bfr[i] = *reinterpret_cast<const bf16x8*>(
            Bb + (wc + i * 16 + l16) * 64 + kk * 32 + lhi * 8);
      }
#pragma unroll
      for (int i = 0; i < 4; ++i)
#pragma unroll
        for (int j = 0; j < 4; ++j)
          acc[i][j] = __builtin_amdgcn_mfma_f32_16x16x32_bf16(
              af[i], bfr[j], acc[i][j], 0, 0, 0);
    }
    __syncthreads();   // drains next-tile loads; guards buffer overwrite
  }

  // ---- epilogue ---- C/D layout: col = lane&15, row = (lane>>4)*4 + reg.
  if (MODE == 0) {
#pragma unroll
    for (int i = 0; i < 4; ++i)
#pragma unroll
      for (int j = 0; j < 4; ++j)
#pragma unroll
        for (int r = 0; r < 4; ++r)
          C[(size_t)(bm + wr + i * 16 + lhi * 4 + r) * N + bn + wc + j * 16 +
            l16] = acc[i][j][r];
  } else if (MODE == 3) {
#pragma unroll
    for (int i = 0; i < 4; ++i)
#pragma unroll
      for (int j = 0; j < 4; ++j) {
        bf16x4 o;
#pragma unroll
        for (int r = 0; r < 4; ++r) o[r] = (__bf16)acc[i][j][r];
        *reinterpret_cast<bf16x4*>(
            &Db[(size_t)(bn + wc + j * 16 + l16) * S_LEN + bm + wr + i * 16 +
                lhi * 4]) = o;
      }
  } else {
    const int dst = (MODE == 1) ? (NH * HD) : (NHK * HD);
    if (wc == 0) {
      // RoPE: head-cols 0..63; fragment pairs (0,2) and (1,3) are (i, i+32).
#pragma unroll
      for (int i = 0; i < 4; ++i)
#pragma unroll
        for (int r = 0; r < 4; ++r) {
          int s = bm + wr + i * 16 + lhi * 4 + r;
          const float* cp = cs + (size_t)s * 64;
          const float* sp = sn + (size_t)s * 64;
          float c0 = cp[l16], c1 = cp[16 + l16];
          float c2 = cp[32 + l16], c3 = cp[48 + l16];
          float s0 = sp[l16], s1 = sp[16 + l16];
          float s2 = sp[32 + l16], s3 = sp[48 + l16];
          float x0 = acc[i][0][r], x1 = acc[i][1][r];
          float x2 = acc[i][2][r], x3 = acc[i][3][r];
          __bf16* dp = Db + (size_t)s * dst + bn;
          dp[l16]      = (__bf16)(x0 * c0 - x2 * s0);
          dp[16 + l16] = (__bf16)(x1 * c1 - x3 * s1);
          dp[32 + l16] = (__bf16)(x2 * c2 + x0 * s2);
          dp[48 + l16] = (__bf16)(x3 * c3 + x1 * s3);
        }
    } else {
#pragma unroll
      for (int i = 0; i < 4; ++i)
#pragma unroll
        for (int j = 0; j < 4; ++j)
#pragma unroll
          for (int r = 0; r < 4; ++r)
            Db[(size_t)(bm + wr + i * 16 + lhi * 4 + r) * dst + bn + wc +
               j * 16 + l16] = (__bf16)acc[i][j][r];
    }
  }
}

__global__ __launch_bounds__(256, 2) void qkv_gemm_kernel(
    const __bf16* __restrict__ hsb, const __bf16* __restrict__ WqT,
    const __bf16* __restrict__ WkT, const __bf16* __restrict__ WvT,
    __bf16* __restrict__ Qbf, __bf16* __restrict__ Kbf,
    __bf16* __restrict__ Vtb, const float* __restrict__ cs,
    const float* __restrict__ sn) {
  __shared__ __attribute__((aligned(16))) __bf16 As[2 * 8192];
  __shared__ __attribute__((aligned(16))) __bf16 Bs[2 * 8192];
  const int bx = blockIdx.x;
  const int bm = blockIdx.y * 128;
  if (bx < 16)
    mfma_gemm_tile_db<1>(As, Bs, hsb, WqT, nullptr, Qbf, cs, sn, 2048, HID_D,
                         bm, bx * 128);
  else if (bx < 20)
    mfma_gemm_tile_db<2>(As, Bs, hsb, WkT, nullptr, Kbf, cs, sn, 512, HID_D,
                         bm, (bx - 16) * 128);
  else
    mfma_gemm_tile_db<3>(As, Bs, hsb, WvT, nullptr, Vtb, cs, sn, 512, HID_D,
                         bm, (bx - 20) * 128);
}

__global__ __launch_bounds__(256, 2) void out_proj_kernel(
    const __bf16* __restrict__ Obf, const __bf16* __restrict__ WoT,
    float* __restrict__ out) {
  __shared__ __attribute__((aligned(16))) __bf16 As[2 * 8192];
  __shared__ __attribute__((aligned(16))) __bf16 Bs[2 * 8192];
  mfma_gemm_tile_db<0>(As, Bs, Obf, WoT, out, nullptr, nullptr, nullptr,
                       HID_D, NH * HD, blockIdx.y * 128, blockIdx.x * 128);
}

// ---------------------------------------------------------------------------
// MFMA bf16 flash attention with sink — double-buffered K/V staging.
// 256 thr (4 waves), BQ=64 (16 q-rows/wave), BK=64. Swapped QK^T; P kept in
// registers and redistributed to PV A-layout via lane shuffles. K/V LDS
// XOR-swizzled (chunk ^= row&7) via pre-swizzled global source.
// ---------------------------------------------------------------------------
__device__ __forceinline__ unsigned pack2_bf16(float a, float b) {
  unsigned short lo = __builtin_bit_cast(unsigned short, (__bf16)a);
  unsigned short hi = __builtin_bit_cast(unsigned short, (__bf16)b);
  return (unsigned)lo | ((unsigned)hi << 16);
}

__global__ __launch_bounds__(256, 2) void attn_mfma_kernel(
    const __bf16* __restrict__ Qbf, const __bf16* __restrict__ Kbf,
    const __bf16* __restrict__ Vtb, const float* __restrict__ sink,
    __bf16* __restrict__ Obf) {
  __shared__ __attribute__((aligned(16))) __bf16 Ks[2 * 64 * 128];  // 32 KB
  __shared__ __attribute__((aligned(16))) __bf16 Vs[2 * 128 * 64];  // 32 KB

  const int tid = threadIdx.x;
  const int wave = tid >> 6, lane = tid & 63;
  const int l16 = lane & 15, lhi = lane >> 4;
  const int h = blockIdx.y;
  const int hk = h >> 2;
  const int qt = (h < 8) ? (31 - (int)blockIdx.x) : (int)blockIdx.x;
  const int q0 = qt * 64;
  const int qrow = q0 + wave * 16 + l16;

  bf16x8 qf[4];
  {
    const __bf16* qp = Qbf + (size_t)qrow * (NH * HD) + h * HD + lhi * 8;
#pragma unroll
    for (int d = 0; d < 4; ++d)
      qf[d] = *reinterpret_cast<const bf16x8*>(qp + d * 32);
  }

  float m = NEG_INF, l_ = 0.f;
  f32x4 acc[8];
#pragma unroll
  for (int f = 0; f < 8; ++f) acc[f] = (f32x4){0.f, 0.f, 0.f, 0.f};

  auto stage_kv = [&](int buf, int kt) {
#pragma unroll
    for (int it = 0; it < 4; ++it) {
      int base = it * 256 + wave * 64;
      int f = base + lane;
      {
        int row = f >> 4, ch = f & 15;
        int sch = (ch & 8) | ((ch ^ row) & 7);
        gload_lds16(Kbf + (size_t)(kt * 64 + row) * (NHK * HD) + hk * HD +
                        sch * 8,
                    Ks + buf * 8192 + base * 8);
      }
      {
        int dv = f >> 3, ch = f & 7;
        int sch = (ch ^ dv) & 7;
        gload_lds16(Vtb + (size_t)(hk * HD + dv) * S_LEN + kt * 64 + sch * 8,
                    Vs + buf * 8192 + base * 8);
      }
    }
  };

  const int xs7 = l16 & 7;
  const int nt = qt + 1;
  stage_kv(0, 0);
  __syncthreads();
  for (int kt = 0; kt < nt; ++kt) {
    const int buf = kt & 1;
    if (kt + 1 < nt) stage_kv(buf ^ 1, kt + 1);   // overlap with compute
    const __bf16* Kb_ = Ks + buf * 8192;
    const __bf16* Vb_ = Vs + buf * 8192;

    // ---- QK^T (swapped) ----
    f32x4 sc[4];
#pragma unroll
    for (int kb = 0; kb < 4; ++kb) sc[kb] = (f32x4){0.f, 0.f, 0.f, 0.f};
#pragma unroll
    for (int d = 0; d < 4; ++d) {
#pragma unroll
      for (int kb = 0; kb < 4; ++kb) {
        int row = kb * 16 + l16;
        int ch = (d * 4 + lhi) ^ xs7;
        bf16x8 kf = *reinterpret_cast<const bf16x8*>(Kb_ + row * 128 + ch * 8);
        sc[kb] = __builtin_amdgcn_mfma_f32_16x16x32_bf16(kf, qf[d], sc[kb],
                                                         0, 0, 0);
      }
    }

    // ---- softmax (per-lane strip of one q-row) ----
    float s[4][4];
    const bool last = (kt == qt);
#pragma unroll
    for (int kb = 0; kb < 4; ++kb)
#pragma unroll
      for (int r = 0; r < 4; ++r) {
        float sv = sc[kb][r] * ATT_SCALE;
        if (last) {
          int kc = kt * 64 + kb * 16 + lhi * 4 + r;
          if (kc > qrow) sv = NEG_INF;
        }
        s[kb][r] = sv;
      }
    float tmax = s[0][0];
#pragma unroll
    for (int kb = 0; kb < 4; ++kb)
#pragma unroll
      for (int r = 0; r < 4; ++r) tmax = fmaxf(tmax, s[kb][r]);
    tmax = fmaxf(tmax, __shfl_xor(tmax, 16));
    tmax = fmaxf(tmax, __shfl_xor(tmax, 32));
    float mn = fmaxf(m, tmax);
    float fac = __expf(m - mn);
    m = mn;
    float p[4][4];
    float rs = 0.f;
#pragma unroll
    for (int kb = 0; kb < 4; ++kb)
#pragma unroll
      for (int r = 0; r < 4; ++r) {
        float pv = __expf(s[kb][r] - mn);
        p[kb][r] = pv;
        rs += pv;
      }
    rs += __shfl_xor(rs, 16);
    rs += __shfl_xor(rs, 32);
    l_ = l_ * fac + rs;

    float facb[4];
#pragma unroll
    for (int r = 0; r < 4; ++r) facb[r] = __shfl(fac, lhi * 4 + r);
#pragma unroll
    for (int f = 0; f < 8; ++f)
#pragma unroll
      for (int r = 0; r < 4; ++r) acc[f][r] *= facb[r];

    // ---- pack P to bf16; redistribute to PV A-layout ----
    unsigned pk[4][2];
#pragma unroll
    for (int kb = 0; kb < 4; ++kb) {
      pk[kb][0] = pack2_bf16(p[kb][0], p[kb][1]);
      pk[kb][1] = pack2_bf16(p[kb][2], p[kb][3]);
    }
    const int s0 = l16 + 16 * (2 * (lhi & 1));
    const int s1 = s0 + 16;
    const bool hihalf = (lhi >= 2);
    bf16x8 pa[2];
#pragma unroll
    for (int c = 0; c < 2; ++c) {
      unsigned aw0 = __shfl((int)pk[2 * c][0], s0);
      unsigned aw1 = __shfl((int)pk[2 * c][1], s0);
      unsigned aw2 = __shfl((int)pk[2 * c][0], s1);
      unsigned aw3 = __shfl((int)pk[2 * c][1], s1);
      unsigned bw0 = __shfl((int)pk[2 * c + 1][0], s0);
      unsigned bw1 = __shfl((int)pk[2 * c + 1][1], s0);
      unsigned bw2 = __shfl((int)pk[2 * c + 1][0], s1);
      unsigned bw3 = __shfl((int)pk[2 * c + 1][1], s1);
      uint4 w;
      w.x = hihalf ? bw0 : aw0;
      w.y = hihalf ? bw1 : aw1;
      w.z = hihalf ? bw2 : aw2;
      w.w = hihalf ? bw3 : aw3;
      pa[c] = __builtin_bit_cast(bf16x8, w);
    }

    // ---- PV ----
#pragma unroll
    for (int c = 0; c < 2; ++c) {
#pragma unroll
      for (int dvf = 0; dvf < 8; ++dvf) {
        int row = dvf * 16 + l16;
        int ch = (c * 4 + lhi) ^ xs7;
        bf16x8 vf = *reinterpret_cast<const bf16x8*>(Vb_ + row * 64 + ch * 8);
        acc[dvf] = __builtin_amdgcn_mfma_f32_16x16x32_bf16(pa[c], vf, acc[dvf],
                                                           0, 0, 0);
      }
    }
    if (kt + 1 < nt) __syncthreads();   // guards next-buffer overwrite
  }

  // ---- epilogue: sink in denominator; store bf16 ----
  float inv = 1.0f / (l_ + __expf(sink[h] - m));
  float invb[4];
#pragma unroll
  for (int r = 0; r < 4; ++r) invb[r] = __shfl(inv, lhi * 4 + r);
#pragma unroll
  for (int dvf = 0; dvf < 8; ++dvf)
#pragma unroll
    for (int r = 0; r < 4; ++r) {
      int row = q0 + wave * 16 + lhi * 4 + r;
      Obf[(size_t)row * (NH * HD) + h * HD + dvf * 16 + l16] =
          (__bf16)(acc[dvf][r] * invb[r]);
    }
}

// ---------------------------------------------------------------------------
extern "C" void kernel_launch(void* const* d_in, const int* in_sizes, int n_in,
                              void* d_out, int out_size, void* d_ws,
                              size_t ws_size, hipStream_t stream) {
  const float* hs   = (const float*)d_in[0];
  const float* cosb = (const float*)d_in[1];
  const float* sinb = (const float*)d_in[2];
  const float* Wq   = (const float*)d_in[3];
  const float* Wk   = (const float*)d_in[4];
  const float* Wv   = (const float*)d_in[5];
  const float* Wo   = (const float*)d_in[6];
  const float* sink = (const float*)d_in[7];
  float* out = (float*)d_out;

  // Workspace (40 MB of bf16 buffers).
  __bf16* hsb = (__bf16*)d_ws;                         // 4M
  __bf16* WqT = hsb + (size_t)S_LEN * HID_D;           // 4M
  __bf16* WkT = WqT + (size_t)HID_D * (NH * HD);       // 1M
  __bf16* WvT = WkT + (size_t)HID_D * (NHK * HD);      // 1M
  __bf16* WoT = WvT + (size_t)HID_D * (NHK * HD);      // 4M
  __bf16* Qbf = WoT + (size_t)(NH * HD) * HID_D;       // 4M
  __bf16* Kbf = Qbf + (size_t)S_LEN * (NH * HD);       // 1M
  __bf16* Vtb = Kbf + (size_t)S_LEN * (NHK * HD);      // 1M
  __bf16* Obf = WqT;   // alias: WqT dead after qkv_gemm

  prep_kernel<<<dim3(6656), 256, 0, stream>>>(hs, Wq, Wk, Wv, Wo, hsb, WqT,
                                              WkT, WvT, WoT);
  qkv_gemm_kernel<<<dim3(24, 16), 256, 0, stream>>>(hsb, WqT, WkT, WvT, Qbf,
                                                    Kbf, Vtb, cosb, sinb);
  attn_mfma_kernel<<<dim3(32, 16), 256, 0, stream>>>(Qbf, Kbf, Vtb, sink, Obf);
  out_proj_kernel<<<dim3(16, 16), 256, 0, stream>>>(Obf, WoT, out);
}

// Round 7
// 259.552 us; speedup vs baseline: 4.7334x; 1.0587x over previous
//
#include <hip/hip_runtime.h>

#define S_LEN 2048
#define HID_D 2048
#define NH 16
#define NHK 4
#define HD 128
#define ATT_SCALE 0.08838834764831845f   // 128^-0.5
#define NEG_INF (-3.0e38f)

typedef __attribute__((ext_vector_type(8))) __bf16 bf16x8;
typedef __attribute__((ext_vector_type(4))) __bf16 bf16x4;
typedef __attribute__((ext_vector_type(4))) float f32x4;

__device__ __forceinline__ void gload_lds16(const void* g, void* l) {
  __builtin_amdgcn_global_load_lds(
      (__attribute__((address_space(1))) void*)g,
      (__attribute__((address_space(3))) void*)l, 16, 0, 0);
}

// ---------------------------------------------------------------------------
// prep: hs f32->bf16 (blocks 0..4095) + 4 weight transposes (blocks 4096..6655)
// ---------------------------------------------------------------------------
__device__ __forceinline__ void transpose_job(
    const float* __restrict__ W, __bf16* __restrict__ WT, int K, int N,
    int local, int nbx, float* Ts /*[64*68]*/) {
  const int t = threadIdx.x;
  const int bk = (local / nbx) * 64, bn = (local % nbx) * 64;
  const int r = t >> 4, c4 = (t & 15) << 2;
#pragma unroll
  for (int i = 0; i < 4; ++i) {
    float4 v = *reinterpret_cast<const float4*>(
        &W[(size_t)(bk + r + 16 * i) * N + bn + c4]);
    *reinterpret_cast<float4*>(&Ts[(r + 16 * i) * 68 + c4]) = v;
  }
  __syncthreads();
#pragma unroll
  for (int i = 0; i < 4; ++i) {
    int n_l = r + 16 * i;
    bf16x4 o;
#pragma unroll
    for (int j = 0; j < 4; ++j) o[j] = (__bf16)Ts[(c4 + j) * 68 + n_l];
    *reinterpret_cast<bf16x4*>(&WT[(size_t)(bn + n_l) * K + bk + c4]) = o;
  }
}

__global__ __launch_bounds__(256) void prep_kernel(
    const float* __restrict__ hs, const float* __restrict__ Wq,
    const float* __restrict__ Wk, const float* __restrict__ Wv,
    const float* __restrict__ Wo, __bf16* __restrict__ hsb,
    __bf16* __restrict__ WqT, __bf16* __restrict__ WkT,
    __bf16* __restrict__ WvT, __bf16* __restrict__ WoT) {
  __shared__ float Ts[64 * 68];
  const int b = blockIdx.x;
  if (b < 4096) {
    int i = b * 256 + threadIdx.x;
    if (i < S_LEN * HID_D / 4) {
      float4 v = *reinterpret_cast<const float4*>(&hs[(size_t)i * 4]);
      bf16x4 o;
      o[0] = (__bf16)v.x; o[1] = (__bf16)v.y;
      o[2] = (__bf16)v.z; o[3] = (__bf16)v.w;
      *reinterpret_cast<bf16x4*>(&hsb[(size_t)i * 4]) = o;
    }
  } else if (b < 5120) {
    transpose_job(Wq, WqT, 2048, 2048, b - 4096, 32, Ts);
  } else if (b < 5376) {
    transpose_job(Wk, WkT, 2048, 512, b - 5120, 8, Ts);
  } else if (b < 5632) {
    transpose_job(Wv, WvT, 2048, 512, b - 5376, 8, Ts);
  } else {
    transpose_job(Wo, WoT, 2048, 2048, b - 5632, 32, Ts);
  }
}

// ---------------------------------------------------------------------------
// Double-buffered MFMA bf16 GEMM tile, XOR-swizzled LDS (stage source chunk
// ^= row&7; fragment read chunk ^= l16&7 — kills the 16-way conflict of the
// 128B-row layout). 128x128 tile, BK=64, 4 waves (2x2 quads).
// MODE 0: fp32 C store.  MODE 1/2: bf16 + fused RoPE (Q / K).
// MODE 3: bf16 transposed store (V^T).  MODE 4: fp32 atomicAdd (split-K).
// ---------------------------------------------------------------------------
template <int MODE>
__device__ __forceinline__ void mfma_gemm_tile_db(
    __bf16* As, __bf16* Bs,   // LDS, [2*8192] each
    const __bf16* __restrict__ A, const __bf16* __restrict__ BT,
    float* __restrict__ C, __bf16* __restrict__ Db,
    const float* __restrict__ cs, const float* __restrict__ sn,
    int N, int K, int bm, int bn, int kbeg, int ksteps) {
  const int tid = threadIdx.x;
  const int wave = tid >> 6, lane = tid & 63;
  const int wr = (wave >> 1) * 64, wc = (wave & 1) * 64;
  const int l16 = lane & 15, lhi = lane >> 4;
  const int xs7 = l16 & 7;

  f32x4 acc[4][4];
#pragma unroll
  for (int i = 0; i < 4; ++i)
#pragma unroll
    for (int j = 0; j < 4; ++j) acc[i][j] = (f32x4){0.f, 0.f, 0.f, 0.f};

  const __bf16* Abase = A + (size_t)bm * K;
  const __bf16* Bbase = BT + (size_t)bn * K;

  auto stage = [&](int buf, int k0) {
#pragma unroll
    for (int it = 0; it < 4; ++it) {
      int base = it * 256 + wave * 64;   // wave-uniform 16B-chunk index
      int f = base + lane;
      int row = f >> 3, ch = f & 7;
      int sch = (ch ^ row) & 7;          // pre-swizzled global source
      gload_lds16(Abase + (size_t)row * K + k0 + sch * 8,
                  As + buf * 8192 + base * 8);
      gload_lds16(Bbase + (size_t)row * K + k0 + sch * 8,
                  Bs + buf * 8192 + base * 8);
    }
  };

  stage(0, kbeg);
  __syncthreads();
  for (int t = 0; t < ksteps; ++t) {
    const int buf = t & 1;
    if (t + 1 < ksteps) stage(buf ^ 1, kbeg + (t + 1) * 64);
    const __bf16* Ab = As + buf * 8192;
    const __bf16* Bb = Bs + buf * 8192;
#pragma unroll
    for (int kk = 0; kk < 2; ++kk) {
      bf16x8 af[4], bfr[4];
#pragma unroll
      for (int i = 0; i < 4; ++i) {
        int ch = (kk * 4 + lhi) ^ xs7;   // swizzled read
        af[i] = *reinterpret_cast<const bf16x8*>(
            Ab + (wr + i * 16 + l16) * 64 + ch * 8);
        bfr[i] = *reinterpret_cast<const bf16x8*>(
            Bb + (wc + i * 16 + l16) * 64 + ch * 8);
      }
#pragma unroll
      for (int i = 0; i < 4; ++i)
#pragma unroll
        for (int j = 0; j < 4; ++j)
          acc[i][j] = __builtin_amdgcn_mfma_f32_16x16x32_bf16(
              af[i], bfr[j], acc[i][j], 0, 0, 0);
    }
    __syncthreads();   // drains next-tile loads; guards buffer overwrite
  }

  // ---- epilogue ---- C/D layout: col = lane&15, row = (lane>>4)*4 + reg.
  if (MODE == 0) {
#pragma unroll
    for (int i = 0; i < 4; ++i)
#pragma unroll
      for (int j = 0; j < 4; ++j)
#pragma unroll
        for (int r = 0; r < 4; ++r)
          C[(size_t)(bm + wr + i * 16 + lhi * 4 + r) * N + bn + wc + j * 16 +
            l16] = acc[i][j][r];
  } else if (MODE == 4) {
#pragma unroll
    for (int i = 0; i < 4; ++i)
#pragma unroll
      for (int j = 0; j < 4; ++j)
#pragma unroll
        for (int r = 0; r < 4; ++r)
          atomicAdd(&C[(size_t)(bm + wr + i * 16 + lhi * 4 + r) * N + bn + wc +
                       j * 16 + l16],
                    acc[i][j][r]);
  } else if (MODE == 3) {
#pragma unroll
    for (int i = 0; i < 4; ++i)
#pragma unroll
      for (int j = 0; j < 4; ++j) {
        bf16x4 o;
#pragma unroll
        for (int r = 0; r < 4; ++r) o[r] = (__bf16)acc[i][j][r];
        *reinterpret_cast<bf16x4*>(
            &Db[(size_t)(bn + wc + j * 16 + l16) * S_LEN + bm + wr + i * 16 +
                lhi * 4]) = o;
      }
  } else {
    const int dst = (MODE == 1) ? (NH * HD) : (NHK * HD);
    if (wc == 0) {
      // RoPE: head-cols 0..63; fragment pairs (0,2) and (1,3) are (i, i+32).
#pragma unroll
      for (int i = 0; i < 4; ++i)
#pragma unroll
        for (int r = 0; r < 4; ++r) {
          int s = bm + wr + i * 16 + lhi * 4 + r;
          const float* cp = cs + (size_t)s * 64;
          const float* sp = sn + (size_t)s * 64;
          float c0 = cp[l16], c1 = cp[16 + l16];
          float c2 = cp[32 + l16], c3 = cp[48 + l16];
          float s0 = sp[l16], s1 = sp[16 + l16];
          float s2 = sp[32 + l16], s3 = sp[48 + l16];
          float x0 = acc[i][0][r], x1 = acc[i][1][r];
          float x2 = acc[i][2][r], x3 = acc[i][3][r];
          __bf16* dp = Db + (size_t)s * dst + bn;
          dp[l16]      = (__bf16)(x0 * c0 - x2 * s0);
          dp[16 + l16] = (__bf16)(x1 * c1 - x3 * s1);
          dp[32 + l16] = (__bf16)(x2 * c2 + x0 * s2);
          dp[48 + l16] = (__bf16)(x3 * c3 + x1 * s3);
        }
    } else {
#pragma unroll
      for (int i = 0; i < 4; ++i)
#pragma unroll
        for (int j = 0; j < 4; ++j)
#pragma unroll
          for (int r = 0; r < 4; ++r)
            Db[(size_t)(bm + wr + i * 16 + lhi * 4 + r) * dst + bn + wc +
               j * 16 + l16] = (__bf16)acc[i][j][r];
    }
  }
}

__global__ __launch_bounds__(256, 2) void qkv_gemm_kernel(
    const __bf16* __restrict__ hsb, const __bf16* __restrict__ WqT,
    const __bf16* __restrict__ WkT, const __bf16* __restrict__ WvT,
    __bf16* __restrict__ Qbf, __bf16* __restrict__ Kbf,
    __bf16* __restrict__ Vtb, const float* __restrict__ cs,
    const float* __restrict__ sn) {
  __shared__ __attribute__((aligned(16))) __bf16 As[2 * 8192];
  __shared__ __attribute__((aligned(16))) __bf16 Bs[2 * 8192];
  const int bx = blockIdx.x;
  const int bm = blockIdx.y * 128;
  if (bx < 16)
    mfma_gemm_tile_db<1>(As, Bs, hsb, WqT, nullptr, Qbf, cs, sn, 2048, HID_D,
                         bm, bx * 128, 0, 32);
  else if (bx < 20)
    mfma_gemm_tile_db<2>(As, Bs, hsb, WkT, nullptr, Kbf, cs, sn, 512, HID_D,
                         bm, (bx - 16) * 128, 0, 32);
  else
    mfma_gemm_tile_db<3>(As, Bs, hsb, WvT, nullptr, Vtb, cs, sn, 512, HID_D,
                         bm, (bx - 20) * 128, 0, 32);
}

// Split-K=2: blockIdx.z picks K-half; partials combined via fp32 atomicAdd
// into d_out (zeroed by hipMemsetAsync before this launch).
__global__ __launch_bounds__(256, 2) void out_proj_kernel(
    const __bf16* __restrict__ Obf, const __bf16* __restrict__ WoT,
    float* __restrict__ out) {
  __shared__ __attribute__((aligned(16))) __bf16 As[2 * 8192];
  __shared__ __attribute__((aligned(16))) __bf16 Bs[2 * 8192];
  mfma_gemm_tile_db<4>(As, Bs, Obf, WoT, out, nullptr, nullptr, nullptr,
                       HID_D, NH * HD, blockIdx.y * 128, blockIdx.x * 128,
                       blockIdx.z * 1024, 16);
}

// ---------------------------------------------------------------------------
// MFMA bf16 flash attention with sink — double-buffered K/V staging +
// defer-max (T13, THR=8). Structure otherwise as round 5/6 (verified).
// ---------------------------------------------------------------------------
__device__ __forceinline__ unsigned pack2_bf16(float a, float b) {
  unsigned short lo = __builtin_bit_cast(unsigned short, (__bf16)a);
  unsigned short hi = __builtin_bit_cast(unsigned short, (__bf16)b);
  return (unsigned)lo | ((unsigned)hi << 16);
}

__global__ __launch_bounds__(256, 2) void attn_mfma_kernel(
    const __bf16* __restrict__ Qbf, const __bf16* __restrict__ Kbf,
    const __bf16* __restrict__ Vtb, const float* __restrict__ sink,
    __bf16* __restrict__ Obf) {
  __shared__ __attribute__((aligned(16))) __bf16 Ks[2 * 64 * 128];  // 32 KB
  __shared__ __attribute__((aligned(16))) __bf16 Vs[2 * 128 * 64];  // 32 KB

  const int tid = threadIdx.x;
  const int wave = tid >> 6, lane = tid & 63;
  const int l16 = lane & 15, lhi = lane >> 4;
  const int h = blockIdx.y;
  const int hk = h >> 2;
  const int qt = (h < 8) ? (31 - (int)blockIdx.x) : (int)blockIdx.x;
  const int q0 = qt * 64;
  const int qrow = q0 + wave * 16 + l16;

  bf16x8 qf[4];
  {
    const __bf16* qp = Qbf + (size_t)qrow * (NH * HD) + h * HD + lhi * 8;
#pragma unroll
    for (int d = 0; d < 4; ++d)
      qf[d] = *reinterpret_cast<const bf16x8*>(qp + d * 32);
  }

  float m = NEG_INF, l_ = 0.f;
  f32x4 acc[8];
#pragma unroll
  for (int f = 0; f < 8; ++f) acc[f] = (f32x4){0.f, 0.f, 0.f, 0.f};

  auto stage_kv = [&](int buf, int kt) {
#pragma unroll
    for (int it = 0; it < 4; ++it) {
      int base = it * 256 + wave * 64;
      int f = base + lane;
      {
        int row = f >> 4, ch = f & 15;
        int sch = (ch & 8) | ((ch ^ row) & 7);
        gload_lds16(Kbf + (size_t)(kt * 64 + row) * (NHK * HD) + hk * HD +
                        sch * 8,
                    Ks + buf * 8192 + base * 8);
      }
      {
        int dv = f >> 3, ch = f & 7;
        int sch = (ch ^ dv) & 7;
        gload_lds16(Vtb + (size_t)(hk * HD + dv) * S_LEN + kt * 64 + sch * 8,
                    Vs + buf * 8192 + base * 8);
      }
    }
  };

  const int xs7 = l16 & 7;
  const int nt = qt + 1;
  stage_kv(0, 0);
  __syncthreads();
  for (int kt = 0; kt < nt; ++kt) {
    const int buf = kt & 1;
    if (kt + 1 < nt) stage_kv(buf ^ 1, kt + 1);   // overlap with compute
    const __bf16* Kb_ = Ks + buf * 8192;
    const __bf16* Vb_ = Vs + buf * 8192;

    // ---- QK^T (swapped) ----
    f32x4 sc[4];
#pragma unroll
    for (int kb = 0; kb < 4; ++kb) sc[kb] = (f32x4){0.f, 0.f, 0.f, 0.f};
#pragma unroll
    for (int d = 0; d < 4; ++d) {
#pragma unroll
      for (int kb = 0; kb < 4; ++kb) {
        int row = kb * 16 + l16;
        int ch = (d * 4 + lhi) ^ xs7;
        bf16x8 kf = *reinterpret_cast<const bf16x8*>(Kb_ + row * 128 + ch * 8);
        sc[kb] = __builtin_amdgcn_mfma_f32_16x16x32_bf16(kf, qf[d], sc[kb],
                                                         0, 0, 0);
      }
    }

    // ---- softmax (per-lane strip of one q-row) ----
    float s[4][4];
    const bool last = (kt == qt);
#pragma unroll
    for (int kb = 0; kb < 4; ++kb)
#pragma unroll
      for (int r = 0; r < 4; ++r) {
        float sv = sc[kb][r] * ATT_SCALE;
        if (last) {
          int kc = kt * 64 + kb * 16 + lhi * 4 + r;
          if (kc > qrow) sv = NEG_INF;
        }
        s[kb][r] = sv;
      }
    float tmax = s[0][0];
#pragma unroll
    for (int kb = 0; kb < 4; ++kb)
#pragma unroll
      for (int r = 0; r < 4; ++r) tmax = fmaxf(tmax, s[kb][r]);
    tmax = fmaxf(tmax, __shfl_xor(tmax, 16));
    tmax = fmaxf(tmax, __shfl_xor(tmax, 32));

    // defer-max (T13): skip rescale when the tile max is within THR of m.
    if (!__all(tmax - m <= 8.0f)) {
      float mn = fmaxf(m, tmax);
      float fac = __expf(m - mn);
      l_ *= fac;
      float facb[4];
#pragma unroll
      for (int r = 0; r < 4; ++r) facb[r] = __shfl(fac, lhi * 4 + r);
#pragma unroll
      for (int f = 0; f < 8; ++f)
#pragma unroll
        for (int r = 0; r < 4; ++r) acc[f][r] *= facb[r];
      m = mn;
    }

    float p[4][4];
    float rs = 0.f;
#pragma unroll
    for (int kb = 0; kb < 4; ++kb)
#pragma unroll
      for (int r = 0; r < 4; ++r) {
        float pv = __expf(s[kb][r] - m);
        p[kb][r] = pv;
        rs += pv;
      }
    rs += __shfl_xor(rs, 16);
    rs += __shfl_xor(rs, 32);
    l_ += rs;

    // ---- pack P to bf16; redistribute to PV A-layout ----
    unsigned pk[4][2];
#pragma unroll
    for (int kb = 0; kb < 4; ++kb) {
      pk[kb][0] = pack2_bf16(p[kb][0], p[kb][1]);
      pk[kb][1] = pack2_bf16(p[kb][2], p[kb][3]);
    }
    const int s0 = l16 + 16 * (2 * (lhi & 1));
    const int s1 = s0 + 16;
    const bool hihalf = (lhi >= 2);
    bf16x8 pa[2];
#pragma unroll
    for (int c = 0; c < 2; ++c) {
      unsigned aw0 = __shfl((int)pk[2 * c][0], s0);
      unsigned aw1 = __shfl((int)pk[2 * c][1], s0);
      unsigned aw2 = __shfl((int)pk[2 * c][0], s1);
      unsigned aw3 = __shfl((int)pk[2 * c][1], s1);
      unsigned bw0 = __shfl((int)pk[2 * c + 1][0], s0);
      unsigned bw1 = __shfl((int)pk[2 * c + 1][1], s0);
      unsigned bw2 = __shfl((int)pk[2 * c + 1][0], s1);
      unsigned bw3 = __shfl((int)pk[2 * c + 1][1], s1);
      uint4 w;
      w.x = hihalf ? bw0 : aw0;
      w.y = hihalf ? bw1 : aw1;
      w.z = hihalf ? bw2 : aw2;
      w.w = hihalf ? bw3 : aw3;
      pa[c] = __builtin_bit_cast(bf16x8, w);
    }

    // ---- PV ----
#pragma unroll
    for (int c = 0; c < 2; ++c) {
#pragma unroll
      for (int dvf = 0; dvf < 8; ++dvf) {
        int row = dvf * 16 + l16;
        int ch = (c * 4 + lhi) ^ xs7;
        bf16x8 vf = *reinterpret_cast<const bf16x8*>(Vb_ + row * 64 + ch * 8);
        acc[dvf] = __builtin_amdgcn_mfma_f32_16x16x32_bf16(pa[c], vf, acc[dvf],
                                                           0, 0, 0);
      }
    }
    if (kt + 1 < nt) __syncthreads();   // guards next-buffer overwrite
  }

  // ---- epilogue: sink in denominator; store bf16 ----
  float inv = 1.0f / (l_ + __expf(sink[h] - m));
  float invb[4];
#pragma unroll
  for (int r = 0; r < 4; ++r) invb[r] = __shfl(inv, lhi * 4 + r);
#pragma unroll
  for (int dvf = 0; dvf < 8; ++dvf)
#pragma unroll
    for (int r = 0; r < 4; ++r) {
      int row = q0 + wave * 16 + lhi * 4 + r;
      Obf[(size_t)row * (NH * HD) + h * HD + dvf * 16 + l16] =
          (__bf16)(acc[dvf][r] * invb[r]);
    }
}

// ---------------------------------------------------------------------------
extern "C" void kernel_launch(void* const* d_in, const int* in_sizes, int n_in,
                              void* d_out, int out_size, void* d_ws,
                              size_t ws_size, hipStream_t stream) {
  const float* hs   = (const float*)d_in[0];
  const float* cosb = (const float*)d_in[1];
  const float* sinb = (const float*)d_in[2];
  const float* Wq   = (const float*)d_in[3];
  const float* Wk   = (const float*)d_in[4];
  const float* Wv   = (const float*)d_in[5];
  const float* Wo   = (const float*)d_in[6];
  const float* sink = (const float*)d_in[7];
  float* out = (float*)d_out;

  // Workspace (40 MB of bf16 buffers).
  __bf16* hsb = (__bf16*)d_ws;                         // 4M
  __bf16* WqT = hsb + (size_t)S_LEN * HID_D;           // 4M
  __bf16* WkT = WqT + (size_t)HID_D * (NH * HD);       // 1M
  __bf16* WvT = WkT + (size_t)HID_D * (NHK * HD);      // 1M
  __bf16* WoT = WvT + (size_t)HID_D * (NHK * HD);      // 4M
  __bf16* Qbf = WoT + (size_t)(NH * HD) * HID_D;       // 4M
  __bf16* Kbf = Qbf + (size_t)S_LEN * (NH * HD);       // 1M
  __bf16* Vtb = Kbf + (size_t)S_LEN * (NHK * HD);      // 1M
  __bf16* Obf = WqT;   // alias: WqT dead after qkv_gemm

  prep_kernel<<<dim3(6656), 256, 0, stream>>>(hs, Wq, Wk, Wv, Wo, hsb, WqT,
                                              WkT, WvT, WoT);
  qkv_gemm_kernel<<<dim3(24, 16), 256, 0, stream>>>(hsb, WqT, WkT, WvT, Qbf,
                                                    Kbf, Vtb, cosb, sinb);
  attn_mfma_kernel<<<dim3(32, 16), 256, 0, stream>>>(Qbf, Kbf, Vtb, sink, Obf);
  // Zero d_out for the split-K atomicAdd combine (graph-capturable).
  hipMemsetAsync(out, 0, (size_t)S_LEN * HID_D * sizeof(float), stream);
  out_proj_kernel<<<dim3(16, 16, 2), 256, 0, stream>>>(Obf, WoT, out);
}

// Round 12
// 230.131 us; speedup vs baseline: 5.3386x; 1.1278x over previous
//
#include <hip/hip_runtime.h>

#define S_LEN 2048
#define HID_D 2048
#define NH 16
#define NHK 4
#define HD 128
#define ATT_SCALE 0.08838834764831845f   // 128^-0.5
#define LOG2E 1.4426950408889634f
#define SCALE2 (ATT_SCALE * LOG2E)       // score scale folded into log2 domain
#define NEG_INF (-3.0e38f)

typedef __attribute__((ext_vector_type(8))) __bf16 bf16x8;
typedef __attribute__((ext_vector_type(4))) __bf16 bf16x4;
typedef __attribute__((ext_vector_type(4))) float f32x4;

#define EXP2F(x) __builtin_amdgcn_exp2f(x)   // raw v_exp_f32

__device__ __forceinline__ void gload_lds16(const void* g, void* l) {
  __builtin_amdgcn_global_load_lds(
      (__attribute__((address_space(1))) void*)g,
      (__attribute__((address_space(3))) void*)l, 16, 0, 0);
}

// ---------------------------------------------------------------------------
// prep: hs f32->bf16 (blocks 0..4095) + 4 weight transposes (blocks 4096..6655)
// ---------------------------------------------------------------------------
__device__ __forceinline__ void transpose_job(
    const float* __restrict__ W, __bf16* __restrict__ WT, int K, int N,
    int local, int nbx, float* Ts /*[64*68]*/) {
  const int t = threadIdx.x;
  const int bk = (local / nbx) * 64, bn = (local % nbx) * 64;
  const int r = t >> 4, c4 = (t & 15) << 2;
#pragma unroll
  for (int i = 0; i < 4; ++i) {
    float4 v = *reinterpret_cast<const float4*>(
        &W[(size_t)(bk + r + 16 * i) * N + bn + c4]);
    *reinterpret_cast<float4*>(&Ts[(r + 16 * i) * 68 + c4]) = v;
  }
  __syncthreads();
#pragma unroll
  for (int i = 0; i < 4; ++i) {
    int n_l = r + 16 * i;
    bf16x4 o;
#pragma unroll
    for (int j = 0; j < 4; ++j) o[j] = (__bf16)Ts[(c4 + j) * 68 + n_l];
    *reinterpret_cast<bf16x4*>(&WT[(size_t)(bn + n_l) * K + bk + c4]) = o;
  }
}

__global__ __launch_bounds__(256) void prep_kernel(
    const float* __restrict__ hs, const float* __restrict__ Wq,
    const float* __restrict__ Wk, const float* __restrict__ Wv,
    const float* __restrict__ Wo, __bf16* __restrict__ hsb,
    __bf16* __restrict__ WqT, __bf16* __restrict__ WkT,
    __bf16* __restrict__ WvT, __bf16* __restrict__ WoT) {
  __shared__ float Ts[64 * 68];
  const int b = blockIdx.x;
  if (b < 4096) {
    int i = b * 256 + threadIdx.x;
    if (i < S_LEN * HID_D / 4) {
      float4 v = *reinterpret_cast<const float4*>(&hs[(size_t)i * 4]);
      bf16x4 o;
      o[0] = (__bf16)v.x; o[1] = (__bf16)v.y;
      o[2] = (__bf16)v.z; o[3] = (__bf16)v.w;
      *reinterpret_cast<bf16x4*>(&hsb[(size_t)i * 4]) = o;
    }
  } else if (b < 5120) {
    transpose_job(Wq, WqT, 2048, 2048, b - 4096, 32, Ts);
  } else if (b < 5376) {
    transpose_job(Wk, WkT, 2048, 512, b - 5120, 8, Ts);
  } else if (b < 5632) {
    transpose_job(Wv, WvT, 2048, 512, b - 5376, 8, Ts);
  } else {
    transpose_job(Wo, WoT, 2048, 2048, b - 5632, 32, Ts);
  }
}

// ---------------------------------------------------------------------------
// Double-buffered MFMA bf16 GEMM tile, BM=64 x BN=128, BK=64, 4 waves
// (wr=(wave>>1)*32, wc=(wave&1)*64; 2x4 fragments/wave). XOR-swizzled LDS
// (stage source chunk ^= row&7; read chunk ^= l16&7). 48 KB LDS -> 3 blk/CU.
// MODE 0: fp32 C store.  MODE 1/2: bf16 + fused RoPE (Q / K).
// MODE 3: bf16 transposed store (V^T).
// ---------------------------------------------------------------------------
template <int MODE>
__device__ __forceinline__ void mfma_gemm_tile_db(
    __bf16* As, __bf16* Bs,   // LDS: As[2*4096], Bs[2*8192]
    const __bf16* __restrict__ A, const __bf16* __restrict__ BT,
    float* __restrict__ C, __bf16* __restrict__ Db,
    const float* __restrict__ cs, const float* __restrict__ sn,
    int N, int K, int bm, int bn) {
  const int tid = threadIdx.x;
  const int wave = tid >> 6, lane = tid & 63;
  const int wr = (wave >> 1) * 32, wc = (wave & 1) * 64;
  const int l16 = lane & 15, lhi = lane >> 4;
  const int xs7 = l16 & 7;

  f32x4 acc[2][4];
#pragma unroll
  for (int i = 0; i < 2; ++i)
#pragma unroll
    for (int j = 0; j < 4; ++j) acc[i][j] = (f32x4){0.f, 0.f, 0.f, 0.f};

  const __bf16* Abase = A + (size_t)bm * K;
  const __bf16* Bbase = BT + (size_t)bn * K;
  const int nk = K >> 6;

  // 1536 16B chunks: A = 0..511 (64 rows x 8), B = 512..1535 (128 rows x 8).
  auto stage = [&](int buf, int k0) {
#pragma unroll
    for (int it = 0; it < 6; ++it) {
      int base = it * 256 + wave * 64;   // wave-uniform chunk base
      int f = base + lane;
      if (base < 512) {
        int row = f >> 3, ch = f & 7;
        int sch = (ch ^ row) & 7;        // pre-swizzled global source
        gload_lds16(Abase + (size_t)row * K + k0 + sch * 8,
                    As + buf * 4096 + base * 8);
      } else {
        int g = f - 512;
        int row = g >> 3, ch = g & 7;
        int sch = (ch ^ row) & 7;
        gload_lds16(Bbase + (size_t)row * K + k0 + sch * 8,
                    Bs + buf * 8192 + (base - 512) * 8);
      }
    }
  };

  stage(0, 0);
  __syncthreads();
  for (int t = 0; t < nk; ++t) {
    const int buf = t & 1;
    if (t + 1 < nk) stage(buf ^ 1, (t + 1) * 64);   // overlap with compute
    const __bf16* Ab = As + buf * 4096;
    const __bf16* Bb = Bs + buf * 8192;
#pragma unroll
    for (int kk = 0; kk < 2; ++kk) {
      int ch = (kk * 4 + lhi) ^ xs7;     // swizzled read
      bf16x8 af[2], bfr[4];
#pragma unroll
      for (int i = 0; i < 2; ++i)
        af[i] = *reinterpret_cast<const bf16x8*>(
            Ab + (wr + i * 16 + l16) * 64 + ch * 8);
#pragma unroll
      for (int j = 0; j < 4; ++j)
        bfr[j] = *reinterpret_cast<const bf16x8*>(
            Bb + (wc + j * 16 + l16) * 64 + ch * 8);
#pragma unroll
      for (int i = 0; i < 2; ++i)
#pragma unroll
        for (int j = 0; j < 4; ++j)
          acc[i][j] = __builtin_amdgcn_mfma_f32_16x16x32_bf16(
              af[i], bfr[j], acc[i][j], 0, 0, 0);
    }
    __syncthreads();   // drains next-tile loads; guards buffer overwrite
  }

  // ---- epilogue ---- C/D layout: col = lane&15, row = (lane>>4)*4 + reg.
  if (MODE == 0) {
#pragma unroll
    for (int i = 0; i < 2; ++i)
#pragma unroll
      for (int j = 0; j < 4; ++j)
#pragma unroll
        for (int r = 0; r < 4; ++r)
          C[(size_t)(bm + wr + i * 16 + lhi * 4 + r) * N + bn + wc + j * 16 +
            l16] = acc[i][j][r];
  } else if (MODE == 3) {
#pragma unroll
    for (int i = 0; i < 2; ++i)
#pragma unroll
      for (int j = 0; j < 4; ++j) {
        bf16x4 o;
#pragma unroll
        for (int r = 0; r < 4; ++r) o[r] = (__bf16)acc[i][j][r];
        *reinterpret_cast<bf16x4*>(
            &Db[(size_t)(bn + wc + j * 16 + l16) * S_LEN + bm + wr + i * 16 +
                lhi * 4]) = o;
      }
  } else {
    const int dst = (MODE == 1) ? (NH * HD) : (NHK * HD);
    if (wc == 0) {
      // RoPE: head-cols 0..63; fragment pairs (0,2) and (1,3) are (i, i+32).
#pragma unroll
      for (int i = 0; i < 2; ++i)
#pragma unroll
        for (int r = 0; r < 4; ++r) {
          int s = bm + wr + i * 16 + lhi * 4 + r;
          const float* cp = cs + (size_t)s * 64;
          const float* sp = sn + (size_t)s * 64;
          float c0 = cp[l16], c1 = cp[16 + l16];
          float c2 = cp[32 + l16], c3 = cp[48 + l16];
          float s0 = sp[l16], s1 = sp[16 + l16];
          float s2 = sp[32 + l16], s3 = sp[48 + l16];
          float x0 = acc[i][0][r], x1 = acc[i][1][r];
          float x2 = acc[i][2][r], x3 = acc[i][3][r];
          __bf16* dp = Db + (size_t)s * dst + bn;
          dp[l16]      = (__bf16)(x0 * c0 - x2 * s0);
          dp[16 + l16] = (__bf16)(x1 * c1 - x3 * s1);
          dp[32 + l16] = (__bf16)(x2 * c2 + x0 * s2);
          dp[48 + l16] = (__bf16)(x3 * c3 + x1 * s3);
        }
    } else {
#pragma unroll
      for (int i = 0; i < 2; ++i)
#pragma unroll
        for (int j = 0; j < 4; ++j)
#pragma unroll
          for (int r = 0; r < 4; ++r)
            Db[(size_t)(bm + wr + i * 16 + lhi * 4 + r) * dst + bn + wc +
               j * 16 + l16] = (__bf16)acc[i][j][r];
    }
  }
}

// grid (24, 32): bx<16 -> Q tile, 16..19 -> K, 20..23 -> V. bm = by*64.
__global__ __launch_bounds__(256, 2) void qkv_gemm_kernel(
    const __bf16* __restrict__ hsb, const __bf16* __restrict__ WqT,
    const __bf16* __restrict__ WkT, const __bf16* __restrict__ WvT,
    __bf16* __restrict__ Qbf, __bf16* __restrict__ Kbf,
    __bf16* __restrict__ Vtb, const float* __restrict__ cs,
    const float* __restrict__ sn) {
  __shared__ __attribute__((aligned(16))) __bf16 As[2 * 4096];
  __shared__ __attribute__((aligned(16))) __bf16 Bs[2 * 8192];
  const int bx = blockIdx.x;
  const int bm = blockIdx.y * 64;
  if (bx < 16)
    mfma_gemm_tile_db<1>(As, Bs, hsb, WqT, nullptr, Qbf, cs, sn, 2048, HID_D,
                         bm, bx * 128);
  else if (bx < 20)
    mfma_gemm_tile_db<2>(As, Bs, hsb, WkT, nullptr, Kbf, cs, sn, 512, HID_D,
                         bm, (bx - 16) * 128);
  else
    mfma_gemm_tile_db<3>(As, Bs, hsb, WvT, nullptr, Vtb, cs, sn, 512, HID_D,
                         bm, (bx - 20) * 128);
}

// grid (16, 32): plain fp32 store, no split-K / atomics.
__global__ __launch_bounds__(256, 2) void out_proj_kernel(
    const __bf16* __restrict__ Obf, const __bf16* __restrict__ WoT,
    float* __restrict__ out) {
  __shared__ __attribute__((aligned(16))) __bf16 As[2 * 4096];
  __shared__ __attribute__((aligned(16))) __bf16 Bs[2 * 8192];
  mfma_gemm_tile_db<0>(As, Bs, Obf, WoT, out, nullptr, nullptr, nullptr,
                       HID_D, NH * HD, blockIdx.y * 64, blockIdx.x * 128);
}

// ---------------------------------------------------------------------------
// MFMA bf16 flash attention with sink — single-buffer staging (R5-proven
// schedule: dbuf regressed at 2 blk/CU), exp2-domain softmax, defer-max,
// setprio around MFMA clusters. 256 thr (4 waves), BQ=64, BK=64.
// ---------------------------------------------------------------------------
__device__ __forceinline__ unsigned pack2_bf16(float a, float b) {
  unsigned short lo = __builtin_bit_cast(unsigned short, (__bf16)a);
  unsigned short hi = __builtin_bit_cast(unsigned short, (__bf16)b);
  return (unsigned)lo | ((unsigned)hi << 16);
}

__global__ __launch_bounds__(256, 2) void attn_mfma_kernel(
    const __bf16* __restrict__ Qbf, const __bf16* __restrict__ Kbf,
    const __bf16* __restrict__ Vtb, const float* __restrict__ sink,
    __bf16* __restrict__ Obf) {
  __shared__ __attribute__((aligned(16))) __bf16 Ks[64 * 128];   // 16 KB
  __shared__ __attribute__((aligned(16))) __bf16 Vs[128 * 64];   // 16 KB

  const int tid = threadIdx.x;
  const int wave = tid >> 6, lane = tid & 63;
  const int l16 = lane & 15, lhi = lane >> 4;
  const int h = blockIdx.y;
  const int hk = h >> 2;
  const int qt = (h < 8) ? (31 - (int)blockIdx.x) : (int)blockIdx.x;
  const int q0 = qt * 64;
  const int qrow = q0 + wave * 16 + l16;

  bf16x8 qf[4];
  {
    const __bf16* qp = Qbf + (size_t)qrow * (NH * HD) + h * HD + lhi * 8;
#pragma unroll
    for (int d = 0; d < 4; ++d)
      qf[d] = *reinterpret_cast<const bf16x8*>(qp + d * 32);
  }

  float m = NEG_INF, l_ = 0.f;   // m, l_ in log2 domain
  f32x4 acc[8];
#pragma unroll
  for (int f = 0; f < 8; ++f) acc[f] = (f32x4){0.f, 0.f, 0.f, 0.f};

  const int xs7 = l16 & 7;
  const int nt = qt + 1;
  for (int kt = 0; kt < nt; ++kt) {
    // ---- stage K (64x16 chunks) and V^T (128x8 chunks), swizzled ----
#pragma unroll
    for (int it = 0; it < 4; ++it) {
      int base = it * 256 + wave * 64;
      int f = base + lane;
      {
        int row = f >> 4, ch = f & 15;
        int sch = (ch & 8) | ((ch ^ row) & 7);
        gload_lds16(Kbf + (size_t)(kt * 64 + row) * (NHK * HD) + hk * HD +
                        sch * 8,
                    Ks + base * 8);
      }
      {
        int dv = f >> 3, ch = f & 7;
        int sch = (ch ^ dv) & 7;
        gload_lds16(Vtb + (size_t)(hk * HD + dv) * S_LEN + kt * 64 + sch * 8,
                    Vs + base * 8);
      }
    }
    __syncthreads();

    // ---- QK^T (swapped) ----
    f32x4 sc[4];
#pragma unroll
    for (int kb = 0; kb < 4; ++kb) sc[kb] = (f32x4){0.f, 0.f, 0.f, 0.f};
    __builtin_amdgcn_s_setprio(1);
#pragma unroll
    for (int d = 0; d < 4; ++d) {
#pragma unroll
      for (int kb = 0; kb < 4; ++kb) {
        int row = kb * 16 + l16;
        int ch = (d * 4 + lhi) ^ xs7;
        bf16x8 kf = *reinterpret_cast<const bf16x8*>(Ks + row * 128 + ch * 8);
        sc[kb] = __builtin_amdgcn_mfma_f32_16x16x32_bf16(kf, qf[d], sc[kb],
                                                         0, 0, 0);
      }
    }
    __builtin_amdgcn_s_setprio(0);

    // ---- softmax in log2 domain (per-lane strip of one q-row) ----
    float s[4][4];
    const bool last = (kt == qt);
#pragma unroll
    for (int kb = 0; kb < 4; ++kb)
#pragma unroll
      for (int r = 0; r < 4; ++r) {
        float sv = sc[kb][r] * SCALE2;
        if (last) {
          int kc = kt * 64 + kb * 16 + lhi * 4 + r;
          if (kc > qrow) sv = NEG_INF;
        }
        s[kb][r] = sv;
      }
    float tmax = s[0][0];
#pragma unroll
    for (int kb = 0; kb < 4; ++kb)
#pragma unroll
      for (int r = 0; r < 4; ++r) tmax = fmaxf(tmax, s[kb][r]);
    tmax = fmaxf(tmax, __shfl_xor(tmax, 16));
    tmax = fmaxf(tmax, __shfl_xor(tmax, 32));

    // defer-max (T13): threshold 8 nats = 11.54 bits.
    if (!__all(tmax - m <= 11.54f)) {
      float mn = fmaxf(m, tmax);
      float fac = EXP2F(m - mn);
      l_ *= fac;
      float facb[4];
#pragma unroll
      for (int r = 0; r < 4; ++r) facb[r] = __shfl(fac, lhi * 4 + r);
#pragma unroll
      for (int f = 0; f < 8; ++f)
#pragma unroll
        for (int r = 0; r < 4; ++r) acc[f][r] *= facb[r];
      m = mn;
    }

    float p[4][4];
    float rs = 0.f;
#pragma unroll
    for (int kb = 0; kb < 4; ++kb)
#pragma unroll
      for (int r = 0; r < 4; ++r) {
        float pv = EXP2F(s[kb][r] - m);
        p[kb][r] = pv;
        rs += pv;
      }
    rs += __shfl_xor(rs, 16);
    rs += __shfl_xor(rs, 32);
    l_ += rs;

    // ---- pack P to bf16; redistribute to PV A-layout ----
    unsigned pk[4][2];
#pragma unroll
    for (int kb = 0; kb < 4; ++kb) {
      pk[kb][0] = pack2_bf16(p[kb][0], p[kb][1]);
      pk[kb][1] = pack2_bf16(p[kb][2], p[kb][3]);
    }
    const int s0 = l16 + 16 * (2 * (lhi & 1));
    const int s1 = s0 + 16;
    const bool hihalf = (lhi >= 2);
    bf16x8 pa[2];
#pragma unroll
    for (int c = 0; c < 2; ++c) {
      unsigned aw0 = __shfl((int)pk[2 * c][0], s0);
      unsigned aw1 = __shfl((int)pk[2 * c][1], s0);
      unsigned aw2 = __shfl((int)pk[2 * c][0], s1);
      unsigned aw3 = __shfl((int)pk[2 * c][1], s1);
      unsigned bw0 = __shfl((int)pk[2 * c + 1][0], s0);
      unsigned bw1 = __shfl((int)pk[2 * c + 1][1], s0);
      unsigned bw2 = __shfl((int)pk[2 * c + 1][0], s1);
      unsigned bw3 = __shfl((int)pk[2 * c + 1][1], s1);
      uint4 w;
      w.x = hihalf ? bw0 : aw0;
      w.y = hihalf ? bw1 : aw1;
      w.z = hihalf ? bw2 : aw2;
      w.w = hihalf ? bw3 : aw3;
      pa[c] = __builtin_bit_cast(bf16x8, w);
    }

    // ---- PV ----
    __builtin_amdgcn_s_setprio(1);
#pragma unroll
    for (int c = 0; c < 2; ++c) {
#pragma unroll
      for (int dvf = 0; dvf < 8; ++dvf) {
        int row = dvf * 16 + l16;
        int ch = (c * 4 + lhi) ^ xs7;
        bf16x8 vf = *reinterpret_cast<const bf16x8*>(Vs + row * 64 + ch * 8);
        acc[dvf] = __builtin_amdgcn_mfma_f32_16x16x32_bf16(pa[c], vf, acc[dvf],
                                                           0, 0, 0);
      }
    }
    __builtin_amdgcn_s_setprio(0);
    if (kt + 1 < nt) __syncthreads();   // reads done before next stage
  }

  // ---- epilogue: sink in denominator (log2 domain); store bf16 ----
  float inv = 1.0f / (l_ + EXP2F(sink[h] * LOG2E - m));
  float invb[4];
#pragma unroll
  for (int r = 0; r < 4; ++r) invb[r] = __shfl(inv, lhi * 4 + r);
#pragma unroll
  for (int dvf = 0; dvf < 8; ++dvf)
#pragma unroll
    for (int r = 0; r < 4; ++r) {
      int row = q0 + wave * 16 + lhi * 4 + r;
      Obf[(size_t)row * (NH * HD) + h * HD + dvf * 16 + l16] =
          (__bf16)(acc[dvf][r] * invb[r]);
    }
}

// ---------------------------------------------------------------------------
extern "C" void kernel_launch(void* const* d_in, const int* in_sizes, int n_in,
                              void* d_out, int out_size, void* d_ws,
                              size_t ws_size, hipStream_t stream) {
  const float* hs   = (const float*)d_in[0];
  const float* cosb = (const float*)d_in[1];
  const float* sinb = (const float*)d_in[2];
  const float* Wq   = (const float*)d_in[3];
  const float* Wk   = (const float*)d_in[4];
  const float* Wv   = (const float*)d_in[5];
  const float* Wo   = (const float*)d_in[6];
  const float* sink = (const float*)d_in[7];
  float* out = (float*)d_out;

  // Workspace (40 MB of bf16 buffers).
  __bf16* hsb = (__bf16*)d_ws;                         // 4M
  __bf16* WqT = hsb + (size_t)S_LEN * HID_D;           // 4M
  __bf16* WkT = WqT + (size_t)HID_D * (NH * HD);       // 1M
  __bf16* WvT = WkT + (size_t)HID_D * (NHK * HD);      // 1M
  __bf16* WoT = WvT + (size_t)HID_D * (NHK * HD);      // 4M
  __bf16* Qbf = WoT + (size_t)(NH * HD) * HID_D;       // 4M
  __bf16* Kbf = Qbf + (size_t)S_LEN * (NH * HD);       // 1M
  __bf16* Vtb = Kbf + (size_t)S_LEN * (NHK * HD);      // 1M
  __bf16* Obf = WqT;   // alias: WqT dead after qkv_gemm

  prep_kernel<<<dim3(6656), 256, 0, stream>>>(hs, Wq, Wk, Wv, Wo, hsb, WqT,
                                              WkT, WvT, WoT);
  qkv_gemm_kernel<<<dim3(24, 32), 256, 0, stream>>>(hsb, WqT, WkT, WvT, Qbf,
                                                    Kbf, Vtb, cosb, sinb);
  attn_mfma_kernel<<<dim3(32, 16), 256, 0, stream>>>(Qbf, Kbf, Vtb, sink, Obf);
  out_proj_kernel<<<dim3(16, 32), 256, 0, stream>>>(Obf, WoT, out);
}